// Round 2
// baseline (499.918 us; speedup 1.0000x reference)
//
#include <hip/hip_runtime.h>

typedef unsigned short u16;
typedef unsigned int u32;
typedef short bf16x8 __attribute__((ext_vector_type(8)));
typedef float f32x4 __attribute__((ext_vector_type(4)));

#define AS1 __attribute__((address_space(1)))
#define AS3 __attribute__((address_space(3)))

#define B_ 2
#define T_ 2048
#define DIM_ 1024
#define HID_ 4096
#define H_ 16
#define KVH_ 4
#define HD_ 64
#define WIN_ 512

__device__ __forceinline__ u16 f2bf(float f) {
    union { float f; u32 u; } v; v.f = f;
    u32 r = v.u + 0x7FFFu + ((v.u >> 16) & 1u);
    return (u16)(r >> 16);
}
__device__ __forceinline__ float bf2f(u16 u) {
    union { u32 u; float f; } v; v.u = ((u32)u) << 16;
    return v.f;
}
__device__ __forceinline__ void load_lds16(const void* g, void* l) {
    __builtin_amdgcn_global_load_lds((AS1 void*)(g), (AS3 void*)(l), 16, 0, 0);
}

// ---------------- mega convert: all weights fp32 -> bf16 in one launch ----------------
// regions (float4 units): wq[0,262144) wk[..327680) wv[..393216) -> wqkv stacked (dst idx == i)
// wo[..655360) ; w1[..1703936) -> w13i even rows ; w3[..2752512) -> w13i odd rows ; w2[..3801088)
__global__ __launch_bounds__(256) void mega_cvt(const float* __restrict__ wq,
                                                const float* __restrict__ wk,
                                                const float* __restrict__ wv,
                                                const float* __restrict__ wo,
                                                const float* __restrict__ w1,
                                                const float* __restrict__ w3,
                                                const float* __restrict__ w2,
                                                u16* __restrict__ wqkv,
                                                u16* __restrict__ wo_b,
                                                u16* __restrict__ w13i,
                                                u16* __restrict__ w2_b) {
    int i = blockIdx.x * 256 + threadIdx.x;  // global float4 index, < 3801088
    const float* s; uint2* dbase; size_t didx;
    if (i < 262144)       { s = wq + (size_t)i * 4;            dbase = (uint2*)wqkv; didx = i; }
    else if (i < 327680)  { int f = i - 262144; s = wk + (size_t)f * 4; dbase = (uint2*)wqkv; didx = 262144 + f; }
    else if (i < 393216)  { int f = i - 327680; s = wv + (size_t)f * 4; dbase = (uint2*)wqkv; didx = 327680 + f; }
    else if (i < 655360)  { int f = i - 393216; s = wo + (size_t)f * 4; dbase = (uint2*)wo_b; didx = f; }
    else if (i < 1703936) { int f = i - 655360; s = w1 + (size_t)f * 4; dbase = (uint2*)w13i;
                            didx = (size_t)((f >> 8) * 2) * 256 + (f & 255); }
    else if (i < 2752512) { int f = i - 1703936; s = w3 + (size_t)f * 4; dbase = (uint2*)w13i;
                            didx = (size_t)((f >> 8) * 2 + 1) * 256 + (f & 255); }
    else                  { int f = i - 2752512; s = w2 + (size_t)f * 4; dbase = (uint2*)w2_b; didx = f; }
    float4 v = *(const float4*)s;
    u32 lo = (u32)f2bf(v.x) | ((u32)f2bf(v.y) << 16);
    u32 hi = (u32)f2bf(v.z) | ((u32)f2bf(v.w) << 16);
    dbase[didx] = make_uint2(lo, hi);
}

// ---------------- RMSNorm (fp32 in, bf16 out), dim=1024 ----------------
__global__ __launch_bounds__(256) void rmsnorm_kernel(const float* __restrict__ x,
                                                      const float* __restrict__ w,
                                                      u16* __restrict__ out, float eps) {
    int row = blockIdx.x, tid = threadIdx.x;
    const float4 v = ((const float4*)(x + (size_t)row * DIM_))[tid];
    float ss = v.x * v.x + v.y * v.y + v.z * v.z + v.w * v.w;
#pragma unroll
    for (int m = 1; m < 64; m <<= 1) ss += __shfl_xor(ss, m);
    __shared__ float part[4];
    if ((tid & 63) == 0) part[tid >> 6] = ss;
    __syncthreads();
    float tot = part[0] + part[1] + part[2] + part[3];
    float r = rsqrtf(tot * (1.0f / DIM_) + eps);
    const float4 wv = ((const float4*)w)[tid];
    u32 lo = (u32)f2bf(v.x * r * wv.x) | ((u32)f2bf(v.y * r * wv.y) << 16);
    u32 hi = (u32)f2bf(v.z * r * wv.z) | ((u32)f2bf(v.w * r * wv.w) << 16);
    ((uint2*)(out + (size_t)row * DIM_))[tid] = make_uint2(lo, hi);
}

// ---------------- QKV post: per-head RMSNorm(eps 1e-6) + bf16 pack ----------------
__global__ __launch_bounds__(256) void qkv_post_kernel(const float* __restrict__ qkv,
                                                       const float* __restrict__ qw,
                                                       const float* __restrict__ kw,
                                                       u16* __restrict__ Qb,
                                                       u16* __restrict__ Kb,
                                                       u16* __restrict__ Vb) {
    int bt = blockIdx.x;
    int b = bt >> 11, t = bt & (T_ - 1);
    int wave = threadIdx.x >> 6, lane = threadIdx.x & 63;
    const float* row = qkv + (size_t)bt * 1536;
    float qwl = qw[lane], kwl = kw[lane];
#pragma unroll
    for (int i = 0; i < 4; i++) {
        int h = wave * 4 + i;
        float v = row[h * 64 + lane];
        float ss = v * v;
#pragma unroll
        for (int m = 1; m < 64; m <<= 1) ss += __shfl_xor(ss, m);
        float r = rsqrtf(ss * (1.0f / 64.0f) + 1e-6f);
        Qb[(((size_t)(b * H_ + h)) * T_ + t) * HD_ + lane] = f2bf(v * r * qwl);
    }
    {
        float v = row[1024 + wave * 64 + lane];
        float ss = v * v;
#pragma unroll
        for (int m = 1; m < 64; m <<= 1) ss += __shfl_xor(ss, m);
        float r = rsqrtf(ss * (1.0f / 64.0f) + 1e-6f);
        Kb[(((size_t)(b * KVH_ + wave)) * T_ + t) * HD_ + lane] = f2bf(v * r * kwl);
        float vv = row[1280 + wave * 64 + lane];
        Vb[(((size_t)(b * KVH_ + wave)) * T_ + t) * HD_ + lane] = f2bf(vv);
    }
}

// ---------------- Flash attention, sliding window 512, GQA 16/4 ----------------
__global__ __launch_bounds__(256) void flash_kernel(const u16* __restrict__ Qb,
                                                    const u16* __restrict__ Kb,
                                                    const u16* __restrict__ Vb,
                                                    u16* __restrict__ Ob) {
    const int b = blockIdx.z, h = blockIdx.y, qt = blockIdx.x;
    const int q0 = qt * 64;
    const int tid = threadIdx.x, wave = tid >> 6, lane = tid & 63;
    const int m = lane & 15, quad = lane >> 4;
    const int kvh = h >> 2;

    __shared__ __align__(16) u16 Ks[32 * 64];   // [k][d]
    __shared__ __align__(16) u16 Vts[64 * 32];  // [d][k]
    __shared__ __align__(16) u16 Ps[4][16 * 32]; // per-wave P tile [q][k]

    const u16* Qp = Qb + ((size_t)(b * H_ + h) * T_) * HD_;
    const u16* Kp = Kb + ((size_t)(b * KVH_ + kvh) * T_) * HD_;
    const u16* Vp = Vb + ((size_t)(b * KVH_ + kvh) * T_) * HD_;

    const int qrow = q0 + wave * 16 + m;
    bf16x8 qa0 = *(const bf16x8*)(Qp + (size_t)qrow * 64 + quad * 8);
    bf16x8 qa1 = *(const bf16x8*)(Qp + (size_t)qrow * 64 + 32 + quad * 8);

    f32x4 o0 = {0.f, 0.f, 0.f, 0.f}, o1 = {0.f, 0.f, 0.f, 0.f};
    f32x4 o2 = {0.f, 0.f, 0.f, 0.f}, o3 = {0.f, 0.f, 0.f, 0.f};
    float mrun[4] = {-INFINITY, -INFINITY, -INFINITY, -INFINITY};
    float lrun[4] = {0.f, 0.f, 0.f, 0.f};

    const int klo = (q0 - (WIN_ - 1) > 0) ? (q0 - (WIN_ - 1)) : 0;
    const int kt0 = klo >> 5, kt1 = (q0 + 63) >> 5;
    const int qlo_w = q0 + wave * 16, qhi_w = qlo_w + 15;

    for (int kt = kt0; kt <= kt1; ++kt) {
        const int kbase = kt << 5;
        __syncthreads();
        {   // stage K [32][64] and V transposed [64][32]
            int flat = tid * 8;
            int kr = flat >> 6, d = flat & 63;
            *(bf16x8*)&Ks[flat] = *(const bf16x8*)(Kp + (size_t)(kbase + kr) * 64 + d);
            bf16x8 vv = *(const bf16x8*)(Vp + (size_t)(kbase + kr) * 64 + d);
#pragma unroll
            for (int jj = 0; jj < 8; jj++) Vts[(d + jj) * 32 + kr] = (u16)vv[jj];
        }
        __syncthreads();
        bool active = (kbase <= qhi_w) && (kbase + 31 >= qlo_w - (WIN_ - 1));
        if (active) {
            f32x4 s0 = {0.f, 0.f, 0.f, 0.f}, s1 = {0.f, 0.f, 0.f, 0.f};
            bf16x8 k00 = *(const bf16x8*)&Ks[m * 64 + quad * 8];
            bf16x8 k01 = *(const bf16x8*)&Ks[m * 64 + 32 + quad * 8];
            bf16x8 k10 = *(const bf16x8*)&Ks[(m + 16) * 64 + quad * 8];
            bf16x8 k11 = *(const bf16x8*)&Ks[(m + 16) * 64 + 32 + quad * 8];
            s0 = __builtin_amdgcn_mfma_f32_16x16x32_bf16(qa0, k00, s0, 0, 0, 0);
            s0 = __builtin_amdgcn_mfma_f32_16x16x32_bf16(qa1, k01, s0, 0, 0, 0);
            s1 = __builtin_amdgcn_mfma_f32_16x16x32_bf16(qa0, k10, s1, 0, 0, 0);
            s1 = __builtin_amdgcn_mfma_f32_16x16x32_bf16(qa1, k11, s1, 0, 0, 0);
#pragma unroll
            for (int r = 0; r < 4; r++) {
                int qg = q0 + wave * 16 + quad * 4 + r;
                int kg0 = kbase + m, kg1 = kbase + 16 + m;
                float v0 = (kg0 <= qg && qg - kg0 < WIN_) ? s0[r] * 0.125f : -INFINITY;
                float v1 = (kg1 <= qg && qg - kg1 < WIN_) ? s1[r] * 0.125f : -INFINITY;
                float rmax = fmaxf(v0, v1);
                rmax = fmaxf(rmax, __shfl_xor(rmax, 1));
                rmax = fmaxf(rmax, __shfl_xor(rmax, 2));
                rmax = fmaxf(rmax, __shfl_xor(rmax, 4));
                rmax = fmaxf(rmax, __shfl_xor(rmax, 8));
                float mnew = fmaxf(mrun[r], rmax);
                float alpha, p0, p1;
                if (mnew == -INFINITY) { alpha = 1.f; p0 = 0.f; p1 = 0.f; }
                else {
                    alpha = __expf(mrun[r] - mnew);
                    p0 = __expf(v0 - mnew);
                    p1 = __expf(v1 - mnew);
                }
                float psum = p0 + p1;
                psum += __shfl_xor(psum, 1);
                psum += __shfl_xor(psum, 2);
                psum += __shfl_xor(psum, 4);
                psum += __shfl_xor(psum, 8);
                lrun[r] = lrun[r] * alpha + psum;
                mrun[r] = mnew;
                o0[r] *= alpha; o1[r] *= alpha; o2[r] *= alpha; o3[r] *= alpha;
                Ps[wave][(quad * 4 + r) * 32 + m] = f2bf(p0);
                Ps[wave][(quad * 4 + r) * 32 + 16 + m] = f2bf(p1);
            }
            bf16x8 pa = *(const bf16x8*)&Ps[wave][m * 32 + quad * 8];
            bf16x8 vb0 = *(const bf16x8*)&Vts[(0 + m) * 32 + quad * 8];
            bf16x8 vb1 = *(const bf16x8*)&Vts[(16 + m) * 32 + quad * 8];
            bf16x8 vb2 = *(const bf16x8*)&Vts[(32 + m) * 32 + quad * 8];
            bf16x8 vb3 = *(const bf16x8*)&Vts[(48 + m) * 32 + quad * 8];
            o0 = __builtin_amdgcn_mfma_f32_16x16x32_bf16(pa, vb0, o0, 0, 0, 0);
            o1 = __builtin_amdgcn_mfma_f32_16x16x32_bf16(pa, vb1, o1, 0, 0, 0);
            o2 = __builtin_amdgcn_mfma_f32_16x16x32_bf16(pa, vb2, o2, 0, 0, 0);
            o3 = __builtin_amdgcn_mfma_f32_16x16x32_bf16(pa, vb3, o3, 0, 0, 0);
        }
    }
#pragma unroll
    for (int r = 0; r < 4; r++) {
        int qg = q0 + wave * 16 + quad * 4 + r;
        float inv = 1.0f / lrun[r];
        size_t base = ((size_t)(b * T_ + qg)) * (H_ * HD_) + h * HD_;
        Ob[base + 0 + m] = f2bf(o0[r] * inv);
        Ob[base + 16 + m] = f2bf(o1[r] * inv);
        Ob[base + 32 + m] = f2bf(o2[r] * inv);
        Ob[base + 48 + m] = f2bf(o3[r] * inv);
    }
}

// ---------------- GEMM: C[M][N] = A[M][K] * Bt[N][K]^T (m97 structure) ----------------
// MODE 0: Cf = acc (fp32).
// MODE 3: split-K partial: unsafeAtomicAdd(Cf, acc*scale[col]); Cf prefilled with residual.
// MODE 4: fused SwiGLU (w1/w3 interleaved cols): Cb[row][col>>1] = bf16(silu(g1)*g3), stride N/2.
template <int MODE>
__global__ __launch_bounds__(256) void gemm_bt(const u16* __restrict__ A,
                                               const u16* __restrict__ Bt,
                                               float* __restrict__ Cf,
                                               u16* __restrict__ Cb,
                                               const float* __restrict__ scale,
                                               int M, int N, int K, int KS) {
    __shared__ __align__(16) u16 As[128 * 32];
    __shared__ __align__(16) u16 Bs[128 * 32];
    const int tid = threadIdx.x, wave = tid >> 6, lane = tid & 63;
    const int m = lane & 15, quad = lane >> 4;
    const int m0 = blockIdx.y * 128, n0 = blockIdx.x * 128;
    const int wm = (wave >> 1) * 64, wn = (wave & 1) * 64;
    const int kb = blockIdx.z * KS, ke = kb + KS;

    f32x4 acc[4][4] = {};

    for (int k0 = kb; k0 < ke; k0 += 32) {
        __syncthreads();
#pragma unroll
        for (int j = 0; j < 2; j++) {
            int slot = wave * 2 + j;
            int flat = slot * 512 + lane * 8;
            int row = flat >> 5, col = flat & 31;
            load_lds16(A + (size_t)(m0 + row) * K + k0 + col, &As[slot * 512]);
            load_lds16(Bt + (size_t)(n0 + row) * K + k0 + col, &Bs[slot * 512]);
        }
        __syncthreads();
        bf16x8 af[4], bfr[4];
#pragma unroll
        for (int i = 0; i < 4; i++) af[i] = *(const bf16x8*)&As[(wm + i * 16 + m) * 32 + quad * 8];
#pragma unroll
        for (int j = 0; j < 4; j++) bfr[j] = *(const bf16x8*)&Bs[(wn + j * 16 + m) * 32 + quad * 8];
#pragma unroll
        for (int i = 0; i < 4; i++)
#pragma unroll
            for (int j = 0; j < 4; j++)
                acc[i][j] = __builtin_amdgcn_mfma_f32_16x16x32_bf16(af[i], bfr[j], acc[i][j], 0, 0, 0);
    }

#pragma unroll
    for (int i = 0; i < 4; i++) {
        int rowb = m0 + wm + i * 16 + quad * 4;
#pragma unroll
        for (int j = 0; j < 4; j++) {
            int col = n0 + wn + j * 16 + m;
            float sc = (MODE == 3) ? scale[col] : 0.f;
#pragma unroll
            for (int r = 0; r < 4; r++) {
                float v = acc[i][j][r];
                if (MODE == 0) {
                    Cf[(size_t)(rowb + r) * N + col] = v;
                } else if (MODE == 3) {
                    unsafeAtomicAdd(&Cf[(size_t)(rowb + r) * N + col], v * sc);
                } else {  // MODE 4
                    float p = __shfl_xor(v, 1);
                    float g1 = (m & 1) ? p : v;
                    float g3 = (m & 1) ? v : p;
                    float res = (g1 / (1.f + __expf(-g1))) * g3;
                    if (!(m & 1))
                        Cb[(size_t)(rowb + r) * (N >> 1) + (col >> 1)] = f2bf(res);
                }
            }
        }
    }
}

extern "C" void kernel_launch(void* const* d_in, const int* in_sizes, int n_in,
                              void* d_out, int out_size, void* d_ws, size_t ws_size,
                              hipStream_t stream) {
    const float* x = (const float*)d_in[0];
    const float* wq = (const float*)d_in[1];
    const float* wk = (const float*)d_in[2];
    const float* wv = (const float*)d_in[3];
    const float* wo = (const float*)d_in[4];
    const float* w1 = (const float*)d_in[5];
    const float* w2 = (const float*)d_in[6];
    const float* w3 = (const float*)d_in[7];
    const float* qnw = (const float*)d_in[8];
    const float* knw = (const float*)d_in[9];
    const float* anw = (const float*)d_in[10];
    const float* fnw = (const float*)d_in[11];
    const float* ascale = (const float*)d_in[12];
    const float* fscale = (const float*)d_in[13];
    float* out = (float*)d_out;

    // ---- workspace layout (non-overlapping, ~129 MiB) ----
    char* ws = (char*)d_ws;
    u16* wqkv_bf = (u16*)(ws + 0);             // [1536][1024]
    u16* wo_bf = (u16*)(ws + 3145728);         // [1024][1024]
    u16* w13i_bf = (u16*)(ws + 5242880);       // [8192][1024] interleaved w1/w3 rows
    u16* w2_bf = (u16*)(ws + 22020096);        // [1024][4096]
    u16* xn_bf = (u16*)(ws + 30408704);        // [4096][1024] (xn, then hn)
    float* qkv_f = (float*)(ws + 38797312);    // [4096][1536] fp32
    u16* Qb = (u16*)(ws + 63963136);           // [2][16][2048][64]
    u16* Kb = (u16*)(ws + 72351744);           // [2][4][2048][64]
    u16* Vb = (u16*)(ws + 74448896);           // [2][4][2048][64]
    u16* att_bf = (u16*)(ws + 76546048);       // [4096][1024]
    float* h_f = (float*)(ws + 84934656);      // [4096][1024] fp32
    u16* gsw_bf = (u16*)(ws + 101711872);      // [4096][4096]

    // residual prefill: h = x (wo GEMM atomically adds r*attn_scale)
    hipMemcpyAsync(h_f, x, (size_t)4096 * 1024 * 4, hipMemcpyDeviceToDevice, stream);
    // all weight converts in one launch (w1/w3 interleaved into w13i)
    mega_cvt<<<14848, 256, 0, stream>>>(wq, wk, wv, wo, w1, w3, w2,
                                        wqkv_bf, wo_bf, w13i_bf, w2_bf);
    // attn-input RMSNorm
    rmsnorm_kernel<<<4096, 256, 0, stream>>>(x, anw, xn_bf, 1e-5f);
    // QKV projection
    gemm_bt<0><<<dim3(12, 32, 1), 256, 0, stream>>>(xn_bf, wqkv_bf, qkv_f, nullptr,
                                                    nullptr, 4096, 1536, 1024, 1024);
    // QK norm + pack
    qkv_post_kernel<<<4096, 256, 0, stream>>>(qkv_f, qnw, knw, Qb, Kb, Vb);
    // sliding-window flash attention
    flash_kernel<<<dim3(32, 16, 2), 256, 0, stream>>>(Qb, Kb, Vb, att_bf);
    // out-proj, split-K=2, atomic: h += r*attn_scale
    gemm_bt<3><<<dim3(8, 32, 2), 256, 0, stream>>>(att_bf, wo_bf, h_f, nullptr,
                                                   ascale, 4096, 1024, 1024, 512);
    // ffn-input RMSNorm
    rmsnorm_kernel<<<4096, 256, 0, stream>>>(h_f, fnw, xn_bf, 1e-5f);
    // residual prefill: out = h (w2 GEMM atomically adds ffn*ffn_scale)
    hipMemcpyAsync(out, h_f, (size_t)4096 * 1024 * 4, hipMemcpyDeviceToDevice, stream);
    // w1|w3 projection with fused SwiGLU epilogue -> gsw [4096][4096] bf16
    gemm_bt<4><<<dim3(64, 32, 1), 256, 0, stream>>>(xn_bf, w13i_bf, nullptr, gsw_bf,
                                                    nullptr, 4096, 8192, 1024, 1024);
    // w2 projection, split-K=4, atomic: out += ffn*ffn_scale
    gemm_bt<3><<<dim3(8, 32, 4), 256, 0, stream>>>(gsw_bf, w2_bf, out, nullptr,
                                                   fscale, 4096, 1024, 4096, 1024);
}

// Round 3
// 444.128 us; speedup vs baseline: 1.1256x; 1.1256x over previous
//
#include <hip/hip_runtime.h>

typedef unsigned short u16;
typedef unsigned int u32;
typedef short bf16x8 __attribute__((ext_vector_type(8)));
typedef float f32x4 __attribute__((ext_vector_type(4)));

#define AS1 __attribute__((address_space(1)))
#define AS3 __attribute__((address_space(3)))

#define B_ 2
#define T_ 2048
#define DIM_ 1024
#define HID_ 4096
#define H_ 16
#define KVH_ 4
#define HD_ 64
#define WIN_ 512

__device__ __forceinline__ u16 f2bf(float f) {
    union { float f; u32 u; } v; v.f = f;
    u32 r = v.u + 0x7FFFu + ((v.u >> 16) & 1u);
    return (u16)(r >> 16);
}
__device__ __forceinline__ void load_lds16(const void* g, void* l) {
    __builtin_amdgcn_global_load_lds((AS1 void*)(g), (AS3 void*)(l), 16, 0, 0);
}

// ---------------- mega convert: all weights fp32 -> bf16 in one launch ----------------
// w1/w3 interleaved at 16-col-tile granularity:
//   real col c, type t(0=w1,1=w3) -> packed row n = (c>>6)*128 + ((c>>5)&1)*64 + ((c>>4)&1)*32 + t*16 + (c&15)
__global__ __launch_bounds__(256) void mega_cvt(const float* __restrict__ wq,
                                                const float* __restrict__ wk,
                                                const float* __restrict__ wv,
                                                const float* __restrict__ wo,
                                                const float* __restrict__ w1,
                                                const float* __restrict__ w3,
                                                const float* __restrict__ w2,
                                                u16* __restrict__ wqkv,
                                                u16* __restrict__ wo_b,
                                                u16* __restrict__ w13i,
                                                u16* __restrict__ w2_b) {
    int i = blockIdx.x * 256 + threadIdx.x;  // global float4 index, < 3801088
    const float* s; uint2* dbase; size_t didx;
    if (i < 262144)       { s = wq + (size_t)i * 4;            dbase = (uint2*)wqkv; didx = i; }
    else if (i < 327680)  { int f = i - 262144; s = wk + (size_t)f * 4; dbase = (uint2*)wqkv; didx = 262144 + f; }
    else if (i < 393216)  { int f = i - 327680; s = wv + (size_t)f * 4; dbase = (uint2*)wqkv; didx = 327680 + f; }
    else if (i < 655360)  { int f = i - 393216; s = wo + (size_t)f * 4; dbase = (uint2*)wo_b; didx = f; }
    else if (i < 1703936) { int f = i - 655360; int c = f >> 8;
                            int n = (c >> 6) * 128 + ((c >> 5) & 1) * 64 + ((c >> 4) & 1) * 32 + (c & 15);
                            s = w1 + (size_t)f * 4; dbase = (uint2*)w13i; didx = (size_t)n * 256 + (f & 255); }
    else if (i < 2752512) { int f = i - 1703936; int c = f >> 8;
                            int n = (c >> 6) * 128 + ((c >> 5) & 1) * 64 + ((c >> 4) & 1) * 32 + 16 + (c & 15);
                            s = w3 + (size_t)f * 4; dbase = (uint2*)w13i; didx = (size_t)n * 256 + (f & 255); }
    else                  { int f = i - 2752512; s = w2 + (size_t)f * 4; dbase = (uint2*)w2_b; didx = f; }
    float4 v = *(const float4*)s;
    u32 lo = (u32)f2bf(v.x) | ((u32)f2bf(v.y) << 16);
    u32 hi = (u32)f2bf(v.z) | ((u32)f2bf(v.w) << 16);
    dbase[didx] = make_uint2(lo, hi);
}

// ---------------- RMSNorm (fp32 in, bf16 out), dim=1024 ----------------
__global__ __launch_bounds__(256) void rmsnorm_kernel(const float* __restrict__ x,
                                                      const float* __restrict__ w,
                                                      u16* __restrict__ out, float eps) {
    int row = blockIdx.x, tid = threadIdx.x;
    const float4 v = ((const float4*)(x + (size_t)row * DIM_))[tid];
    float ss = v.x * v.x + v.y * v.y + v.z * v.z + v.w * v.w;
#pragma unroll
    for (int m = 1; m < 64; m <<= 1) ss += __shfl_xor(ss, m);
    __shared__ float part[4];
    if ((tid & 63) == 0) part[tid >> 6] = ss;
    __syncthreads();
    float tot = part[0] + part[1] + part[2] + part[3];
    float r = rsqrtf(tot * (1.0f / DIM_) + eps);
    const float4 wv = ((const float4*)w)[tid];
    u32 lo = (u32)f2bf(v.x * r * wv.x) | ((u32)f2bf(v.y * r * wv.y) << 16);
    u32 hi = (u32)f2bf(v.z * r * wv.z) | ((u32)f2bf(v.w * r * wv.w) << 16);
    ((uint2*)(out + (size_t)row * DIM_))[tid] = make_uint2(lo, hi);
}

// ---------------- fuse_attn: h = x + (p0+p1)*ascale; xn = rmsnorm(h)*fnw ----------------
__global__ __launch_bounds__(256) void fuse_attn_kernel(const float* __restrict__ x,
                                                        const float* __restrict__ p,
                                                        const float* __restrict__ ascale,
                                                        const float* __restrict__ fnw,
                                                        float* __restrict__ h,
                                                        u16* __restrict__ xn) {
    int row = blockIdx.x, tid = threadIdx.x;
    const float4 xv = ((const float4*)(x + (size_t)row * DIM_))[tid];
    const float4 a0 = ((const float4*)(p + (size_t)row * DIM_))[tid];
    const float4 a1 = ((const float4*)(p + 4194304 + (size_t)row * DIM_))[tid];
    const float4 sc = ((const float4*)ascale)[tid];
    float4 hv;
    hv.x = xv.x + (a0.x + a1.x) * sc.x;
    hv.y = xv.y + (a0.y + a1.y) * sc.y;
    hv.z = xv.z + (a0.z + a1.z) * sc.z;
    hv.w = xv.w + (a0.w + a1.w) * sc.w;
    ((float4*)(h + (size_t)row * DIM_))[tid] = hv;
    float ss = hv.x * hv.x + hv.y * hv.y + hv.z * hv.z + hv.w * hv.w;
#pragma unroll
    for (int m = 1; m < 64; m <<= 1) ss += __shfl_xor(ss, m);
    __shared__ float part[4];
    if ((tid & 63) == 0) part[tid >> 6] = ss;
    __syncthreads();
    float tot = part[0] + part[1] + part[2] + part[3];
    float r = rsqrtf(tot * (1.0f / DIM_) + 1e-5f);
    const float4 wv = ((const float4*)fnw)[tid];
    u32 lo = (u32)f2bf(hv.x * r * wv.x) | ((u32)f2bf(hv.y * r * wv.y) << 16);
    u32 hi = (u32)f2bf(hv.z * r * wv.z) | ((u32)f2bf(hv.w * r * wv.w) << 16);
    ((uint2*)(xn + (size_t)row * DIM_))[tid] = make_uint2(lo, hi);
}

// ---------------- fuse_ffn: out = h + (p0+p1+p2+p3)*fscale ----------------
__global__ __launch_bounds__(256) void fuse_ffn_kernel(const float* __restrict__ h,
                                                       const float* __restrict__ p,
                                                       const float* __restrict__ fscale,
                                                       float* __restrict__ out) {
    int row = blockIdx.x, tid = threadIdx.x;
    const float4 hv = ((const float4*)(h + (size_t)row * DIM_))[tid];
    const float4 a0 = ((const float4*)(p + (size_t)row * DIM_))[tid];
    const float4 a1 = ((const float4*)(p + 4194304 + (size_t)row * DIM_))[tid];
    const float4 a2 = ((const float4*)(p + 8388608 + (size_t)row * DIM_))[tid];
    const float4 a3 = ((const float4*)(p + 12582912 + (size_t)row * DIM_))[tid];
    const float4 sc = ((const float4*)fscale)[tid];
    float4 o;
    o.x = hv.x + (a0.x + a1.x + a2.x + a3.x) * sc.x;
    o.y = hv.y + (a0.y + a1.y + a2.y + a3.y) * sc.y;
    o.z = hv.z + (a0.z + a1.z + a2.z + a3.z) * sc.z;
    o.w = hv.w + (a0.w + a1.w + a2.w + a3.w) * sc.w;
    ((float4*)(out + (size_t)row * DIM_))[tid] = o;
}

// ---------------- QKV post: sum 2 partials + per-head RMSNorm(1e-6) + bf16 pack ----------------
__global__ __launch_bounds__(256) void qkv_post_kernel(const float* __restrict__ qkv,
                                                       const float* __restrict__ qw,
                                                       const float* __restrict__ kw,
                                                       u16* __restrict__ Qb,
                                                       u16* __restrict__ Kb,
                                                       u16* __restrict__ Vb) {
    int bt = blockIdx.x;
    int b = bt >> 11, t = bt & (T_ - 1);
    int wave = threadIdx.x >> 6, lane = threadIdx.x & 63;
    const float* row0 = qkv + (size_t)bt * 1536;
    const float* row1 = row0 + 6291456;  // partial 1
    float qwl = qw[lane], kwl = kw[lane];
#pragma unroll
    for (int i = 0; i < 4; i++) {
        int h = wave * 4 + i;
        float v = row0[h * 64 + lane] + row1[h * 64 + lane];
        float ss = v * v;
#pragma unroll
        for (int m = 1; m < 64; m <<= 1) ss += __shfl_xor(ss, m);
        float r = rsqrtf(ss * (1.0f / 64.0f) + 1e-6f);
        Qb[(((size_t)(b * H_ + h)) * T_ + t) * HD_ + lane] = f2bf(v * r * qwl);
    }
    {
        float v = row0[1024 + wave * 64 + lane] + row1[1024 + wave * 64 + lane];
        float ss = v * v;
#pragma unroll
        for (int m = 1; m < 64; m <<= 1) ss += __shfl_xor(ss, m);
        float r = rsqrtf(ss * (1.0f / 64.0f) + 1e-6f);
        Kb[(((size_t)(b * KVH_ + wave)) * T_ + t) * HD_ + lane] = f2bf(v * r * kwl);
        float vv = row0[1280 + wave * 64 + lane] + row1[1280 + wave * 64 + lane];
        Vb[(((size_t)(b * KVH_ + wave)) * T_ + t) * HD_ + lane] = f2bf(vv);
    }
}

// ---------------- Flash attention, sliding window 512, GQA 16/4 ----------------
__global__ __launch_bounds__(256) void flash_kernel(const u16* __restrict__ Qb,
                                                    const u16* __restrict__ Kb,
                                                    const u16* __restrict__ Vb,
                                                    u16* __restrict__ Ob) {
    const int b = blockIdx.z, h = blockIdx.y, qt = blockIdx.x;
    const int q0 = qt * 64;
    const int tid = threadIdx.x, wave = tid >> 6, lane = tid & 63;
    const int m = lane & 15, quad = lane >> 4;
    const int kvh = h >> 2;

    __shared__ __align__(16) u16 Ks[32 * 64];
    __shared__ __align__(16) u16 Vts[64 * 32];
    __shared__ __align__(16) u16 Ps[4][16 * 32];

    const u16* Qp = Qb + ((size_t)(b * H_ + h) * T_) * HD_;
    const u16* Kp = Kb + ((size_t)(b * KVH_ + kvh) * T_) * HD_;
    const u16* Vp = Vb + ((size_t)(b * KVH_ + kvh) * T_) * HD_;

    const int qrow = q0 + wave * 16 + m;
    bf16x8 qa0 = *(const bf16x8*)(Qp + (size_t)qrow * 64 + quad * 8);
    bf16x8 qa1 = *(const bf16x8*)(Qp + (size_t)qrow * 64 + 32 + quad * 8);

    f32x4 o0 = {0.f, 0.f, 0.f, 0.f}, o1 = {0.f, 0.f, 0.f, 0.f};
    f32x4 o2 = {0.f, 0.f, 0.f, 0.f}, o3 = {0.f, 0.f, 0.f, 0.f};
    float mrun[4] = {-INFINITY, -INFINITY, -INFINITY, -INFINITY};
    float lrun[4] = {0.f, 0.f, 0.f, 0.f};

    const int klo = (q0 - (WIN_ - 1) > 0) ? (q0 - (WIN_ - 1)) : 0;
    const int kt0 = klo >> 5, kt1 = (q0 + 63) >> 5;
    const int qlo_w = q0 + wave * 16, qhi_w = qlo_w + 15;

    for (int kt = kt0; kt <= kt1; ++kt) {
        const int kbase = kt << 5;
        __syncthreads();
        {
            int flat = tid * 8;
            int kr = flat >> 6, d = flat & 63;
            *(bf16x8*)&Ks[flat] = *(const bf16x8*)(Kp + (size_t)(kbase + kr) * 64 + d);
            bf16x8 vv = *(const bf16x8*)(Vp + (size_t)(kbase + kr) * 64 + d);
#pragma unroll
            for (int jj = 0; jj < 8; jj++) Vts[(d + jj) * 32 + kr] = (u16)vv[jj];
        }
        __syncthreads();
        bool active = (kbase <= qhi_w) && (kbase + 31 >= qlo_w - (WIN_ - 1));
        if (active) {
            f32x4 s0 = {0.f, 0.f, 0.f, 0.f}, s1 = {0.f, 0.f, 0.f, 0.f};
            bf16x8 k00 = *(const bf16x8*)&Ks[m * 64 + quad * 8];
            bf16x8 k01 = *(const bf16x8*)&Ks[m * 64 + 32 + quad * 8];
            bf16x8 k10 = *(const bf16x8*)&Ks[(m + 16) * 64 + quad * 8];
            bf16x8 k11 = *(const bf16x8*)&Ks[(m + 16) * 64 + 32 + quad * 8];
            s0 = __builtin_amdgcn_mfma_f32_16x16x32_bf16(qa0, k00, s0, 0, 0, 0);
            s0 = __builtin_amdgcn_mfma_f32_16x16x32_bf16(qa1, k01, s0, 0, 0, 0);
            s1 = __builtin_amdgcn_mfma_f32_16x16x32_bf16(qa0, k10, s1, 0, 0, 0);
            s1 = __builtin_amdgcn_mfma_f32_16x16x32_bf16(qa1, k11, s1, 0, 0, 0);
#pragma unroll
            for (int r = 0; r < 4; r++) {
                int qg = q0 + wave * 16 + quad * 4 + r;
                int kg0 = kbase + m, kg1 = kbase + 16 + m;
                float v0 = (kg0 <= qg && qg - kg0 < WIN_) ? s0[r] * 0.125f : -INFINITY;
                float v1 = (kg1 <= qg && qg - kg1 < WIN_) ? s1[r] * 0.125f : -INFINITY;
                float rmax = fmaxf(v0, v1);
                rmax = fmaxf(rmax, __shfl_xor(rmax, 1));
                rmax = fmaxf(rmax, __shfl_xor(rmax, 2));
                rmax = fmaxf(rmax, __shfl_xor(rmax, 4));
                rmax = fmaxf(rmax, __shfl_xor(rmax, 8));
                float mnew = fmaxf(mrun[r], rmax);
                float alpha, p0, p1;
                if (mnew == -INFINITY) { alpha = 1.f; p0 = 0.f; p1 = 0.f; }
                else {
                    alpha = __expf(mrun[r] - mnew);
                    p0 = __expf(v0 - mnew);
                    p1 = __expf(v1 - mnew);
                }
                float psum = p0 + p1;
                psum += __shfl_xor(psum, 1);
                psum += __shfl_xor(psum, 2);
                psum += __shfl_xor(psum, 4);
                psum += __shfl_xor(psum, 8);
                lrun[r] = lrun[r] * alpha + psum;
                mrun[r] = mnew;
                o0[r] *= alpha; o1[r] *= alpha; o2[r] *= alpha; o3[r] *= alpha;
                Ps[wave][(quad * 4 + r) * 32 + m] = f2bf(p0);
                Ps[wave][(quad * 4 + r) * 32 + 16 + m] = f2bf(p1);
            }
            bf16x8 pa = *(const bf16x8*)&Ps[wave][m * 32 + quad * 8];
            bf16x8 vb0 = *(const bf16x8*)&Vts[(0 + m) * 32 + quad * 8];
            bf16x8 vb1 = *(const bf16x8*)&Vts[(16 + m) * 32 + quad * 8];
            bf16x8 vb2 = *(const bf16x8*)&Vts[(32 + m) * 32 + quad * 8];
            bf16x8 vb3 = *(const bf16x8*)&Vts[(48 + m) * 32 + quad * 8];
            o0 = __builtin_amdgcn_mfma_f32_16x16x32_bf16(pa, vb0, o0, 0, 0, 0);
            o1 = __builtin_amdgcn_mfma_f32_16x16x32_bf16(pa, vb1, o1, 0, 0, 0);
            o2 = __builtin_amdgcn_mfma_f32_16x16x32_bf16(pa, vb2, o2, 0, 0, 0);
            o3 = __builtin_amdgcn_mfma_f32_16x16x32_bf16(pa, vb3, o3, 0, 0, 0);
        }
    }
#pragma unroll
    for (int r = 0; r < 4; r++) {
        int qg = q0 + wave * 16 + quad * 4 + r;
        float inv = 1.0f / lrun[r];
        size_t base = ((size_t)(b * T_ + qg)) * (H_ * HD_) + h * HD_;
        Ob[base + 0 + m] = f2bf(o0[r] * inv);
        Ob[base + 16 + m] = f2bf(o1[r] * inv);
        Ob[base + 32 + m] = f2bf(o2[r] * inv);
        Ob[base + 48 + m] = f2bf(o3[r] * inv);
    }
}

// ---------------- GEMM: C[M][N] = A[M][K] * Bt[N][K]^T (m97 structure) ----------------
// MODE 0: Cf[z*M*N + idx] = acc (fp32 partials; z = blockIdx.z K-slice).
// MODE 4: fused SwiGLU, w1/w3 interleaved at 16-col tiles: per lane g1=acc[i][2jp], g3=acc[i][2jp+1].
template <int MODE>
__global__ __launch_bounds__(256) void gemm_bt(const u16* __restrict__ A,
                                               const u16* __restrict__ Bt,
                                               float* __restrict__ Cf,
                                               u16* __restrict__ Cb,
                                               int M, int N, int K, int KS) {
    __shared__ __align__(16) u16 As[128 * 32];
    __shared__ __align__(16) u16 Bs[128 * 32];
    const int tid = threadIdx.x, wave = tid >> 6, lane = tid & 63;
    const int m = lane & 15, quad = lane >> 4;
    const int m0 = blockIdx.y * 128, n0 = blockIdx.x * 128;
    const int wm = (wave >> 1) * 64, wn = (wave & 1) * 64;
    const int kb = blockIdx.z * KS, ke = kb + KS;

    f32x4 acc[4][4] = {};

    for (int k0 = kb; k0 < ke; k0 += 32) {
        __syncthreads();
#pragma unroll
        for (int j = 0; j < 2; j++) {
            int slot = wave * 2 + j;
            int flat = slot * 512 + lane * 8;
            int row = flat >> 5, col = flat & 31;
            load_lds16(A + (size_t)(m0 + row) * K + k0 + col, &As[slot * 512]);
            load_lds16(Bt + (size_t)(n0 + row) * K + k0 + col, &Bs[slot * 512]);
        }
        __syncthreads();
        bf16x8 af[4], bfr[4];
#pragma unroll
        for (int i = 0; i < 4; i++) af[i] = *(const bf16x8*)&As[(wm + i * 16 + m) * 32 + quad * 8];
#pragma unroll
        for (int j = 0; j < 4; j++) bfr[j] = *(const bf16x8*)&Bs[(wn + j * 16 + m) * 32 + quad * 8];
#pragma unroll
        for (int i = 0; i < 4; i++)
#pragma unroll
            for (int j = 0; j < 4; j++)
                acc[i][j] = __builtin_amdgcn_mfma_f32_16x16x32_bf16(af[i], bfr[j], acc[i][j], 0, 0, 0);
    }

    if (MODE == 0) {
        float* Cz = Cf + (size_t)blockIdx.z * M * N;
#pragma unroll
        for (int i = 0; i < 4; i++) {
            int rowb = m0 + wm + i * 16 + quad * 4;
#pragma unroll
            for (int j = 0; j < 4; j++) {
                int col = n0 + wn + j * 16 + m;
#pragma unroll
                for (int r = 0; r < 4; r++)
                    Cz[(size_t)(rowb + r) * N + col] = acc[i][j][r];
            }
        }
    } else {  // MODE 4: SwiGLU epilogue, no cross-lane ops
        const int cbase = (n0 >> 1) + (wn >> 1) + m;
#pragma unroll
        for (int i = 0; i < 4; i++) {
            int rowb = m0 + wm + i * 16 + quad * 4;
#pragma unroll
            for (int jp = 0; jp < 2; jp++) {
                int c = cbase + jp * 16;
#pragma unroll
                for (int r = 0; r < 4; r++) {
                    float g1 = acc[i][2 * jp][r];
                    float g3 = acc[i][2 * jp + 1][r];
                    float res = (g1 / (1.f + __expf(-g1))) * g3;
                    Cb[(size_t)(rowb + r) * (N >> 1) + c] = f2bf(res);
                }
            }
        }
    }
}

extern "C" void kernel_launch(void* const* d_in, const int* in_sizes, int n_in,
                              void* d_out, int out_size, void* d_ws, size_t ws_size,
                              hipStream_t stream) {
    const float* x = (const float*)d_in[0];
    const float* wq = (const float*)d_in[1];
    const float* wk = (const float*)d_in[2];
    const float* wv = (const float*)d_in[3];
    const float* wo = (const float*)d_in[4];
    const float* w1 = (const float*)d_in[5];
    const float* w2 = (const float*)d_in[6];
    const float* w3 = (const float*)d_in[7];
    const float* qnw = (const float*)d_in[8];
    const float* knw = (const float*)d_in[9];
    const float* anw = (const float*)d_in[10];
    const float* fnw = (const float*)d_in[11];
    const float* ascale = (const float*)d_in[12];
    const float* fscale = (const float*)d_in[13];
    float* out = (float*)d_out;

    // ---- workspace layout (overlaid, total 156,237,824 B) ----
    char* ws = (char*)d_ws;
    u16* wqkv_bf = (u16*)(ws + 0);             // [1536][1024]
    u16* wo_bf = (u16*)(ws + 3145728);         // [1024][1024]
    u16* w13i_bf = (u16*)(ws + 5242880);       // [8192][1024] 16-col-tile interleaved
    u16* w2_bf = (u16*)(ws + 22020096);        // [1024][4096]
    u16* xn_bf = (u16*)(ws + 30408704);        // [4096][1024] (xn, then hn)
    char* P = ws + 38797312;                   // overlay pool
    float* qkv_f = (float*)(P + 0);            // 2x[4096][1536] fp32 partials (50.3 MB)
    u16* Qb = (u16*)(P + 50331648);            // 8.4 MB
    u16* Kb = (u16*)(P + 58720256);            // 2.1 MB
    u16* Vb = (u16*)(P + 60817408);            // 2.1 MB
    u16* att_bf = (u16*)(P + 62914560);        // 8.4 MB
    float* wo_part = (float*)(P + 0);          // 2x[4096][1024] fp32 (reuses qkv_f)
    u16* gsw_bf = (u16*)(P + 0);               // [4096][4096] bf16 (reuses wo_part)
    float* w2_part = (float*)(P + 33554432);   // 4x[4096][1024] fp32 (67.1 MB)
    float* h_f = (float*)(P + 100663296);      // [4096][1024] fp32

    // all weight converts in one launch
    mega_cvt<<<14848, 256, 0, stream>>>(wq, wk, wv, wo, w1, w3, w2,
                                        wqkv_bf, wo_bf, w13i_bf, w2_bf);
    // attn-input RMSNorm
    rmsnorm_kernel<<<4096, 256, 0, stream>>>(x, anw, xn_bf, 1e-5f);
    // QKV projection, split-K=2 -> 2 fp32 partials
    gemm_bt<0><<<dim3(12, 32, 2), 256, 0, stream>>>(xn_bf, wqkv_bf, qkv_f, nullptr,
                                                    4096, 1536, 1024, 512);
    // QK norm + pack (sums the 2 partials)
    qkv_post_kernel<<<4096, 256, 0, stream>>>(qkv_f, qnw, knw, Qb, Kb, Vb);
    // sliding-window flash attention
    flash_kernel<<<dim3(32, 16, 2), 256, 0, stream>>>(Qb, Kb, Vb, att_bf);
    // out-proj, split-K=2 -> 2 fp32 partials
    gemm_bt<0><<<dim3(8, 32, 2), 256, 0, stream>>>(att_bf, wo_bf, wo_part, nullptr,
                                                   4096, 1024, 1024, 512);
    // h = x + (p0+p1)*ascale ; xn = rmsnorm(h)*fnw   (fused residual + ffn-norm)
    fuse_attn_kernel<<<4096, 256, 0, stream>>>(x, wo_part, ascale, fnw, h_f, xn_bf);
    // w1|w3 projection with fused SwiGLU epilogue -> gsw [4096][4096] bf16
    gemm_bt<4><<<dim3(64, 32, 1), 256, 0, stream>>>(xn_bf, w13i_bf, nullptr, gsw_bf,
                                                    4096, 8192, 1024, 1024);
    // w2 projection, split-K=4 -> 4 fp32 partials
    gemm_bt<0><<<dim3(8, 32, 4), 256, 0, stream>>>(gsw_bf, w2_bf, w2_part, nullptr,
                                                   4096, 1024, 4096, 1024);
    // out = h + (p0+p1+p2+p3)*fscale
    fuse_ffn_kernel<<<4096, 256, 0, stream>>>(h_f, w2_part, fscale, out);
}

// Round 4
// 388.335 us; speedup vs baseline: 1.2873x; 1.1437x over previous
//
#include <hip/hip_runtime.h>

typedef unsigned short u16;
typedef unsigned int u32;
typedef unsigned char u8;
typedef short bf16x8 __attribute__((ext_vector_type(8)));
typedef float f32x4 __attribute__((ext_vector_type(4)));
typedef float f32x16 __attribute__((ext_vector_type(16)));
typedef int i32x4 __attribute__((ext_vector_type(4)));
typedef int i32x8 __attribute__((ext_vector_type(8)));

#define AS1 __attribute__((address_space(1)))
#define AS3 __attribute__((address_space(3)))

#define B_ 2
#define T_ 2048
#define DIM_ 1024
#define HID_ 4096
#define H_ 16
#define KVH_ 4
#define HD_ 64
#define WIN_ 512

// MX scale bytes: activations stored x8 (descale 2^-3 = 124), weights x64 (2^-6 = 121)
#define SCALE_A 0x7C7C7C7C
#define SCALE_B 0x79797979

__device__ __forceinline__ u16 f2bf(float f) {
    union { float f; u32 u; } v; v.f = f;
    u32 r = v.u + 0x7FFFu + ((v.u >> 16) & 1u);
    return (u16)(r >> 16);
}
__device__ __forceinline__ float bf2f(u32 u) {
    union { u32 u; float f; } v; v.u = u << 16;
    return v.f;
}
__device__ __forceinline__ float4 ld4bf(const u16* p) {
    uint2 u = *(const uint2*)p;
    float4 r;
    r.x = bf2f(u.x & 0xFFFFu); r.y = bf2f(u.x >> 16);
    r.z = bf2f(u.y & 0xFFFFu); r.w = bf2f(u.y >> 16);
    return r;
}
__device__ __forceinline__ void load_lds16(const void* g, void* l) {
    __builtin_amdgcn_global_load_lds((AS1 void*)(g), (AS3 void*)(l), 16, 0, 0);
}

// ---------------- mega convert: bf16 for wqkv/wo, fp8(x64) for w13 (interleaved-32) & w2 ----------------
__global__ __launch_bounds__(256) void mega_cvt(const float* __restrict__ wq,
                                                const float* __restrict__ wk,
                                                const float* __restrict__ wv,
                                                const float* __restrict__ wo,
                                                const float* __restrict__ w1,
                                                const float* __restrict__ w3,
                                                const float* __restrict__ w2,
                                                u16* __restrict__ wqkv,
                                                u16* __restrict__ wo_b,
                                                u8* __restrict__ w13_8,
                                                u8* __restrict__ w2_8) {
    int i = blockIdx.x * 256 + threadIdx.x;  // global float4 index, < 3801088 exactly
    if (i < 655360) {
        const float* s; uint2* dbase; size_t didx;
        if (i < 262144)      { s = wq + (size_t)i * 4; dbase = (uint2*)wqkv; didx = i; }
        else if (i < 327680) { int f = i - 262144; s = wk + (size_t)f * 4; dbase = (uint2*)wqkv; didx = 262144 + f; }
        else if (i < 393216) { int f = i - 327680; s = wv + (size_t)f * 4; dbase = (uint2*)wqkv; didx = 327680 + f; }
        else                 { int f = i - 393216; s = wo + (size_t)f * 4; dbase = (uint2*)wo_b; didx = f; }
        float4 v = *(const float4*)s;
        u32 lo = (u32)f2bf(v.x) | ((u32)f2bf(v.y) << 16);
        u32 hi = (u32)f2bf(v.z) | ((u32)f2bf(v.w) << 16);
        dbase[didx] = make_uint2(lo, hi);
    } else {
        // fp8 e4m3, values x64. w1/w3 interleaved in 32-col tiles:
        //   w1 row c -> packed (c>>5)*64 + (c&31);  w3 row c -> packed (c>>5)*64 + 32 + (c&31)
        const float* s; u32* dbase; size_t didx;
        if (i < 1703936)      { int f = i - 655360;  int c = f >> 8; int n = (c >> 5) * 64 + (c & 31);
                                s = w1 + (size_t)f * 4; dbase = (u32*)w13_8; didx = (size_t)n * 256 + (f & 255); }
        else if (i < 2752512) { int f = i - 1703936; int c = f >> 8; int n = (c >> 5) * 64 + 32 + (c & 31);
                                s = w3 + (size_t)f * 4; dbase = (u32*)w13_8; didx = (size_t)n * 256 + (f & 255); }
        else                  { int f = i - 2752512; s = w2 + (size_t)f * 4; dbase = (u32*)w2_8; didx = f; }
        float4 v = *(const float4*)s;
        int p = __builtin_amdgcn_cvt_pk_fp8_f32(v.x * 64.f, v.y * 64.f, 0, false);
        p = __builtin_amdgcn_cvt_pk_fp8_f32(v.z * 64.f, v.w * 64.f, p, true);
        dbase[didx] = (u32)p;
    }
}

// ---------------- RMSNorm (fp32 in, bf16 out), dim=1024 ----------------
__global__ __launch_bounds__(256) void rmsnorm_kernel(const float* __restrict__ x,
                                                      const float* __restrict__ w,
                                                      u16* __restrict__ out, float eps) {
    int row = blockIdx.x, tid = threadIdx.x;
    const float4 v = ((const float4*)(x + (size_t)row * DIM_))[tid];
    float ss = v.x * v.x + v.y * v.y + v.z * v.z + v.w * v.w;
#pragma unroll
    for (int m = 1; m < 64; m <<= 1) ss += __shfl_xor(ss, m);
    __shared__ float part[4];
    if ((tid & 63) == 0) part[tid >> 6] = ss;
    __syncthreads();
    float tot = part[0] + part[1] + part[2] + part[3];
    float r = rsqrtf(tot * (1.0f / DIM_) + eps);
    const float4 wv = ((const float4*)w)[tid];
    u32 lo = (u32)f2bf(v.x * r * wv.x) | ((u32)f2bf(v.y * r * wv.y) << 16);
    u32 hi = (u32)f2bf(v.z * r * wv.z) | ((u32)f2bf(v.w * r * wv.w) << 16);
    ((uint2*)(out + (size_t)row * DIM_))[tid] = make_uint2(lo, hi);
}

// ---------------- fuse_attn: h = x + (p0+p1)*ascale; xn8 = fp8(rmsnorm(h)*fnw * 8) ----------------
__global__ __launch_bounds__(256) void fuse_attn_kernel(const float* __restrict__ x,
                                                        const u16* __restrict__ p,
                                                        const float* __restrict__ ascale,
                                                        const float* __restrict__ fnw,
                                                        float* __restrict__ h,
                                                        u8* __restrict__ xn8) {
    int row = blockIdx.x, tid = threadIdx.x;
    const float4 xv = ((const float4*)(x + (size_t)row * DIM_))[tid];
    float4 a0 = ld4bf(p + (size_t)row * DIM_ + tid * 4);
    float4 a1 = ld4bf(p + 4194304 + (size_t)row * DIM_ + tid * 4);
    const float4 sc = ((const float4*)ascale)[tid];
    float4 hv;
    hv.x = xv.x + (a0.x + a1.x) * sc.x;
    hv.y = xv.y + (a0.y + a1.y) * sc.y;
    hv.z = xv.z + (a0.z + a1.z) * sc.z;
    hv.w = xv.w + (a0.w + a1.w) * sc.w;
    ((float4*)(h + (size_t)row * DIM_))[tid] = hv;
    float ss = hv.x * hv.x + hv.y * hv.y + hv.z * hv.z + hv.w * hv.w;
#pragma unroll
    for (int m = 1; m < 64; m <<= 1) ss += __shfl_xor(ss, m);
    __shared__ float part[4];
    if ((tid & 63) == 0) part[tid >> 6] = ss;
    __syncthreads();
    float tot = part[0] + part[1] + part[2] + part[3];
    float r = rsqrtf(tot * (1.0f / DIM_) + 1e-5f) * 8.0f;  // x8 for fp8 encoding
    const float4 wv = ((const float4*)fnw)[tid];
    int pk = __builtin_amdgcn_cvt_pk_fp8_f32(hv.x * r * wv.x, hv.y * r * wv.y, 0, false);
    pk = __builtin_amdgcn_cvt_pk_fp8_f32(hv.z * r * wv.z, hv.w * r * wv.w, pk, true);
    ((u32*)xn8)[(size_t)row * 256 + tid] = (u32)pk;
}

// ---------------- fuse_ffn: out = h + (p0+p1+p2+p3)*fscale (bf16 partials) ----------------
__global__ __launch_bounds__(256) void fuse_ffn_kernel(const float* __restrict__ h,
                                                       const u16* __restrict__ p,
                                                       const float* __restrict__ fscale,
                                                       float* __restrict__ out) {
    int row = blockIdx.x, tid = threadIdx.x;
    const float4 hv = ((const float4*)(h + (size_t)row * DIM_))[tid];
    size_t off = (size_t)row * DIM_ + tid * 4;
    float4 a0 = ld4bf(p + off);
    float4 a1 = ld4bf(p + 4194304 + off);
    float4 a2 = ld4bf(p + 8388608 + off);
    float4 a3 = ld4bf(p + 12582912 + off);
    const float4 sc = ((const float4*)fscale)[tid];
    float4 o;
    o.x = hv.x + (a0.x + a1.x + a2.x + a3.x) * sc.x;
    o.y = hv.y + (a0.y + a1.y + a2.y + a3.y) * sc.y;
    o.z = hv.z + (a0.z + a1.z + a2.z + a3.z) * sc.z;
    o.w = hv.w + (a0.w + a1.w + a2.w + a3.w) * sc.w;
    ((float4*)(out + (size_t)row * DIM_))[tid] = o;
}

// ---------------- QKV post: sum 2 bf16 partials + per-head RMSNorm(1e-6) + bf16 pack ----------------
__global__ __launch_bounds__(256) void qkv_post_kernel(const u16* __restrict__ qkv,
                                                       const float* __restrict__ qw,
                                                       const float* __restrict__ kw,
                                                       u16* __restrict__ Qb,
                                                       u16* __restrict__ Kb,
                                                       u16* __restrict__ Vb) {
    int bt = blockIdx.x;
    int b = bt >> 11, t = bt & (T_ - 1);
    int wave = threadIdx.x >> 6, lane = threadIdx.x & 63;
    const u16* row0 = qkv + (size_t)bt * 1536;
    const u16* row1 = row0 + 6291456;
    float qwl = qw[lane], kwl = kw[lane];
#pragma unroll
    for (int i = 0; i < 4; i++) {
        int h = wave * 4 + i;
        float v = bf2f(row0[h * 64 + lane]) + bf2f(row1[h * 64 + lane]);
        float ss = v * v;
#pragma unroll
        for (int m = 1; m < 64; m <<= 1) ss += __shfl_xor(ss, m);
        float r = rsqrtf(ss * (1.0f / 64.0f) + 1e-6f);
        Qb[(((size_t)(b * H_ + h)) * T_ + t) * HD_ + lane] = f2bf(v * r * qwl);
    }
    {
        float v = bf2f(row0[1024 + wave * 64 + lane]) + bf2f(row1[1024 + wave * 64 + lane]);
        float ss = v * v;
#pragma unroll
        for (int m = 1; m < 64; m <<= 1) ss += __shfl_xor(ss, m);
        float r = rsqrtf(ss * (1.0f / 64.0f) + 1e-6f);
        Kb[(((size_t)(b * KVH_ + wave)) * T_ + t) * HD_ + lane] = f2bf(v * r * kwl);
        float vv = bf2f(row0[1280 + wave * 64 + lane]) + bf2f(row1[1280 + wave * 64 + lane]);
        Vb[(((size_t)(b * KVH_ + wave)) * T_ + t) * HD_ + lane] = f2bf(vv);
    }
}

// ---------------- Flash attention, sliding window 512, GQA 16/4 ----------------
__global__ __launch_bounds__(256) void flash_kernel(const u16* __restrict__ Qb,
                                                    const u16* __restrict__ Kb,
                                                    const u16* __restrict__ Vb,
                                                    u16* __restrict__ Ob) {
    const int b = blockIdx.z, h = blockIdx.y, qt = blockIdx.x;
    const int q0 = qt * 64;
    const int tid = threadIdx.x, wave = tid >> 6, lane = tid & 63;
    const int m = lane & 15, quad = lane >> 4;
    const int kvh = h >> 2;

    __shared__ __align__(16) u16 Ks[32 * 64];
    __shared__ __align__(16) u16 Vts[64 * 32];
    __shared__ __align__(16) u16 Ps[4][16 * 32];

    const u16* Qp = Qb + ((size_t)(b * H_ + h) * T_) * HD_;
    const u16* Kp = Kb + ((size_t)(b * KVH_ + kvh) * T_) * HD_;
    const u16* Vp = Vb + ((size_t)(b * KVH_ + kvh) * T_) * HD_;

    const int qrow = q0 + wave * 16 + m;
    bf16x8 qa0 = *(const bf16x8*)(Qp + (size_t)qrow * 64 + quad * 8);
    bf16x8 qa1 = *(const bf16x8*)(Qp + (size_t)qrow * 64 + 32 + quad * 8);

    f32x4 o0 = {0.f, 0.f, 0.f, 0.f}, o1 = {0.f, 0.f, 0.f, 0.f};
    f32x4 o2 = {0.f, 0.f, 0.f, 0.f}, o3 = {0.f, 0.f, 0.f, 0.f};
    float mrun[4] = {-INFINITY, -INFINITY, -INFINITY, -INFINITY};
    float lrun[4] = {0.f, 0.f, 0.f, 0.f};

    const int klo = (q0 - (WIN_ - 1) > 0) ? (q0 - (WIN_ - 1)) : 0;
    const int kt0 = klo >> 5, kt1 = (q0 + 63) >> 5;
    const int qlo_w = q0 + wave * 16, qhi_w = qlo_w + 15;

    for (int kt = kt0; kt <= kt1; ++kt) {
        const int kbase = kt << 5;
        __syncthreads();
        {
            int flat = tid * 8;
            int kr = flat >> 6, d = flat & 63;
            *(bf16x8*)&Ks[flat] = *(const bf16x8*)(Kp + (size_t)(kbase + kr) * 64 + d);
            bf16x8 vv = *(const bf16x8*)(Vp + (size_t)(kbase + kr) * 64 + d);
#pragma unroll
            for (int jj = 0; jj < 8; jj++) Vts[(d + jj) * 32 + kr] = (u16)vv[jj];
        }
        __syncthreads();
        bool active = (kbase <= qhi_w) && (kbase + 31 >= qlo_w - (WIN_ - 1));
        if (active) {
            f32x4 s0 = {0.f, 0.f, 0.f, 0.f}, s1 = {0.f, 0.f, 0.f, 0.f};
            bf16x8 k00 = *(const bf16x8*)&Ks[m * 64 + quad * 8];
            bf16x8 k01 = *(const bf16x8*)&Ks[m * 64 + 32 + quad * 8];
            bf16x8 k10 = *(const bf16x8*)&Ks[(m + 16) * 64 + quad * 8];
            bf16x8 k11 = *(const bf16x8*)&Ks[(m + 16) * 64 + 32 + quad * 8];
            s0 = __builtin_amdgcn_mfma_f32_16x16x32_bf16(qa0, k00, s0, 0, 0, 0);
            s0 = __builtin_amdgcn_mfma_f32_16x16x32_bf16(qa1, k01, s0, 0, 0, 0);
            s1 = __builtin_amdgcn_mfma_f32_16x16x32_bf16(qa0, k10, s1, 0, 0, 0);
            s1 = __builtin_amdgcn_mfma_f32_16x16x32_bf16(qa1, k11, s1, 0, 0, 0);
#pragma unroll
            for (int r = 0; r < 4; r++) {
                int qg = q0 + wave * 16 + quad * 4 + r;
                int kg0 = kbase + m, kg1 = kbase + 16 + m;
                float v0 = (kg0 <= qg && qg - kg0 < WIN_) ? s0[r] * 0.125f : -INFINITY;
                float v1 = (kg1 <= qg && qg - kg1 < WIN_) ? s1[r] * 0.125f : -INFINITY;
                float rmax = fmaxf(v0, v1);
                rmax = fmaxf(rmax, __shfl_xor(rmax, 1));
                rmax = fmaxf(rmax, __shfl_xor(rmax, 2));
                rmax = fmaxf(rmax, __shfl_xor(rmax, 4));
                rmax = fmaxf(rmax, __shfl_xor(rmax, 8));
                float mnew = fmaxf(mrun[r], rmax);
                float alpha, p0, p1;
                if (mnew == -INFINITY) { alpha = 1.f; p0 = 0.f; p1 = 0.f; }
                else {
                    alpha = __expf(mrun[r] - mnew);
                    p0 = __expf(v0 - mnew);
                    p1 = __expf(v1 - mnew);
                }
                float psum = p0 + p1;
                psum += __shfl_xor(psum, 1);
                psum += __shfl_xor(psum, 2);
                psum += __shfl_xor(psum, 4);
                psum += __shfl_xor(psum, 8);
                lrun[r] = lrun[r] * alpha + psum;
                mrun[r] = mnew;
                o0[r] *= alpha; o1[r] *= alpha; o2[r] *= alpha; o3[r] *= alpha;
                Ps[wave][(quad * 4 + r) * 32 + m] = f2bf(p0);
                Ps[wave][(quad * 4 + r) * 32 + 16 + m] = f2bf(p1);
            }
            bf16x8 pa = *(const bf16x8*)&Ps[wave][m * 32 + quad * 8];
            bf16x8 vb0 = *(const bf16x8*)&Vts[(0 + m) * 32 + quad * 8];
            bf16x8 vb1 = *(const bf16x8*)&Vts[(16 + m) * 32 + quad * 8];
            bf16x8 vb2 = *(const bf16x8*)&Vts[(32 + m) * 32 + quad * 8];
            bf16x8 vb3 = *(const bf16x8*)&Vts[(48 + m) * 32 + quad * 8];
            o0 = __builtin_amdgcn_mfma_f32_16x16x32_bf16(pa, vb0, o0, 0, 0, 0);
            o1 = __builtin_amdgcn_mfma_f32_16x16x32_bf16(pa, vb1, o1, 0, 0, 0);
            o2 = __builtin_amdgcn_mfma_f32_16x16x32_bf16(pa, vb2, o2, 0, 0, 0);
            o3 = __builtin_amdgcn_mfma_f32_16x16x32_bf16(pa, vb3, o3, 0, 0, 0);
        }
    }
#pragma unroll
    for (int r = 0; r < 4; r++) {
        int qg = q0 + wave * 16 + quad * 4 + r;
        float inv = 1.0f / lrun[r];
        size_t base = ((size_t)(b * T_ + qg)) * (H_ * HD_) + h * HD_;
        Ob[base + 0 + m] = f2bf(o0[r] * inv);
        Ob[base + 16 + m] = f2bf(o1[r] * inv);
        Ob[base + 32 + m] = f2bf(o2[r] * inv);
        Ob[base + 48 + m] = f2bf(o3[r] * inv);
    }
}

// ---------------- bf16 GEMM (m97): C partials bf16 at z*M*N ----------------
__global__ __launch_bounds__(256) void gemm_bt(const u16* __restrict__ A,
                                               const u16* __restrict__ Bt,
                                               u16* __restrict__ Cb,
                                               int M, int N, int K, int KS) {
    __shared__ __align__(16) u16 As[128 * 32];
    __shared__ __align__(16) u16 Bs[128 * 32];
    const int tid = threadIdx.x, wave = tid >> 6, lane = tid & 63;
    const int m = lane & 15, quad = lane >> 4;
    const int m0 = blockIdx.y * 128, n0 = blockIdx.x * 128;
    const int wm = (wave >> 1) * 64, wn = (wave & 1) * 64;
    const int kb = blockIdx.z * KS, ke = kb + KS;

    f32x4 acc[4][4] = {};

    for (int k0 = kb; k0 < ke; k0 += 32) {
        __syncthreads();
#pragma unroll
        for (int j = 0; j < 2; j++) {
            int slot = wave * 2 + j;
            int flat = slot * 512 + lane * 8;
            int row = flat >> 5, col = flat & 31;
            load_lds16(A + (size_t)(m0 + row) * K + k0 + col, &As[slot * 512]);
            load_lds16(Bt + (size_t)(n0 + row) * K + k0 + col, &Bs[slot * 512]);
        }
        __syncthreads();
        bf16x8 af[4], bfr[4];
#pragma unroll
        for (int i = 0; i < 4; i++) af[i] = *(const bf16x8*)&As[(wm + i * 16 + m) * 32 + quad * 8];
#pragma unroll
        for (int j = 0; j < 4; j++) bfr[j] = *(const bf16x8*)&Bs[(wn + j * 16 + m) * 32 + quad * 8];
#pragma unroll
        for (int i = 0; i < 4; i++)
#pragma unroll
            for (int j = 0; j < 4; j++)
                acc[i][j] = __builtin_amdgcn_mfma_f32_16x16x32_bf16(af[i], bfr[j], acc[i][j], 0, 0, 0);
    }

    u16* Cz = Cb + (size_t)blockIdx.z * M * N;
#pragma unroll
    for (int i = 0; i < 4; i++) {
        int rowb = m0 + wm + i * 16 + quad * 4;
#pragma unroll
        for (int j = 0; j < 4; j++) {
            int col = n0 + wn + j * 16 + m;
#pragma unroll
            for (int r = 0; r < 4; r++)
                Cz[(size_t)(rowb + r) * N + col] = f2bf(acc[i][j][r]);
        }
    }
}

// ---------------- fp8 MX GEMM (32x32x64 f8f6f4, scale-folded) ----------------
// A [M][K] fp8 (x8), Bt [N][K] fp8 (x64). Tile 128x128, BK=64, 4 waves of 64x64 (2x2 32x32).
// LDS layout: granule (c,r) = 16B chunk c (k-dir) of row r -> offset (c*128+r)*16.
// MODE 0: bf16 partials at z*M*N. MODE 1: fused SwiGLU (32-col interleave) -> fp8(x8).
template <int MODE>
__global__ __launch_bounds__(256) void gemm_fp8(const u8* __restrict__ A,
                                                const u8* __restrict__ Bt,
                                                u16* __restrict__ Cb,
                                                u8* __restrict__ C8,
                                                int M, int N, int K, int KS) {
    __shared__ __align__(16) u8 As[8192];
    __shared__ __align__(16) u8 Bs[8192];
    const int tid = threadIdx.x, wave = tid >> 6, lane = tid & 63;
    const int l31 = lane & 31, lh = lane >> 5;
    const int m0 = blockIdx.y * 128, n0 = blockIdx.x * 128;
    const int wm = (wave >> 1) * 64, wn = (wave & 1) * 64;
    const int kb = blockIdx.z * KS, ke = kb + KS;
    const int chunk0 = wave * 2;

    f32x16 acc[2][2] = {};

    for (int k0 = kb; k0 < ke; k0 += 64) {
        __syncthreads();
#pragma unroll
        for (int j = 0; j < 2; j++) {
            int g = (chunk0 + j) * 64 + lane;
            int c = g >> 7, r = g & 127;
            load_lds16(A + (size_t)(m0 + r) * K + k0 + c * 16, &As[(chunk0 + j) * 1024]);
            load_lds16(Bt + (size_t)(n0 + r) * K + k0 + c * 16, &Bs[(chunk0 + j) * 1024]);
        }
        __syncthreads();
        i32x8 af[2], bfr[2];
#pragma unroll
        for (int i = 0; i < 2; i++) {
            union { i32x4 h[2]; i32x8 v; } u;
            u.h[0] = *(const i32x4*)&As[((lh * 2 + 0) * 128 + wm + i * 32 + l31) * 16];
            u.h[1] = *(const i32x4*)&As[((lh * 2 + 1) * 128 + wm + i * 32 + l31) * 16];
            af[i] = u.v;
        }
#pragma unroll
        for (int j = 0; j < 2; j++) {
            union { i32x4 h[2]; i32x8 v; } u;
            u.h[0] = *(const i32x4*)&Bs[((lh * 2 + 0) * 128 + wn + j * 32 + l31) * 16];
            u.h[1] = *(const i32x4*)&Bs[((lh * 2 + 1) * 128 + wn + j * 32 + l31) * 16];
            bfr[j] = u.v;
        }
#pragma unroll
        for (int i = 0; i < 2; i++)
#pragma unroll
            for (int j = 0; j < 2; j++)
                acc[i][j] = __builtin_amdgcn_mfma_scale_f32_32x32x64_f8f6f4(
                    af[i], bfr[j], acc[i][j], 0, 0, 0, SCALE_A, 0, SCALE_B);
    }

    if (MODE == 0) {
        u16* Cz = Cb + (size_t)blockIdx.z * M * N;
#pragma unroll
        for (int i = 0; i < 2; i++)
#pragma unroll
            for (int j = 0; j < 2; j++) {
                int col = n0 + wn + j * 32 + l31;
#pragma unroll
                for (int reg = 0; reg < 16; reg++) {
                    int row = m0 + wm + i * 32 + (reg & 3) + 8 * (reg >> 2) + 4 * lh;
                    Cz[(size_t)row * N + col] = f2bf(acc[i][j][reg]);
                }
            }
    } else {
        // SwiGLU: acc[i][0] = g1-tile, acc[i][1] = g3-tile for same 32 real cols
        int c = (n0 >> 1) + (wn >> 1) + l31;
#pragma unroll
        for (int i = 0; i < 2; i++)
#pragma unroll
            for (int reg = 0; reg < 16; reg++) {
                int row = m0 + wm + i * 32 + (reg & 3) + 8 * (reg >> 2) + 4 * lh;
                float g1 = acc[i][0][reg], g3 = acc[i][1][reg];
                float res = (g1 / (1.f + __expf(-g1))) * g3 * 8.0f;  // x8 for fp8 encoding
                int p = __builtin_amdgcn_cvt_pk_fp8_f32(res, res, 0, false);
                C8[(size_t)row * (N >> 1) + c] = (u8)(p & 0xFF);
            }
    }
}

extern "C" void kernel_launch(void* const* d_in, const int* in_sizes, int n_in,
                              void* d_out, int out_size, void* d_ws, size_t ws_size,
                              hipStream_t stream) {
    const float* x = (const float*)d_in[0];
    const float* wq = (const float*)d_in[1];
    const float* wk = (const float*)d_in[2];
    const float* wv = (const float*)d_in[3];
    const float* wo = (const float*)d_in[4];
    const float* w1 = (const float*)d_in[5];
    const float* w2 = (const float*)d_in[6];
    const float* w3 = (const float*)d_in[7];
    const float* qnw = (const float*)d_in[8];
    const float* knw = (const float*)d_in[9];
    const float* anw = (const float*)d_in[10];
    const float* fnw = (const float*)d_in[11];
    const float* ascale = (const float*)d_in[12];
    const float* fscale = (const float*)d_in[13];
    float* out = (float*)d_out;

    // ---- workspace layout (~109 MiB) ----
    char* ws = (char*)d_ws;
    u16* wqkv_bf = (u16*)(ws + 0);          // [1536][1024] bf16
    u16* wo_bf = (u16*)(ws + 3145728);      // [1024][1024] bf16
    u8* w13_8 = (u8*)(ws + 5242880);        // [8192][1024] fp8 (x64, 32-col interleave)
    u8* w2_8 = (u8*)(ws + 13631488);        // [1024][4096] fp8 (x64)
    u16* xn_bf = (u16*)(ws + 17825792);     // [4096][1024] bf16 (attn-norm out)
    u8* xn8 = (u8*)(ws + 26214400);         // [4096][1024] fp8 (x8, ffn-norm out)
    float* h_f = (float*)(ws + 30408704);   // [4096][1024] fp32
    char* P = ws + 47185920;                // overlay pool (67.1 MB)
    u16* qkv_part = (u16*)(P + 0);          // 2x[4096][1536] bf16 partials
    u16* Qb = (u16*)(P + 25165824);
    u16* Kb = (u16*)(P + 33554432);
    u16* Vb = (u16*)(P + 35651584);
    u16* att_bf = (u16*)(P + 37748736);     // [4096][1024] bf16
    u16* wo_part = (u16*)(P + 0);           // 2x[4096][1024] bf16 (reuses qkv_part)
    u8* gsw8 = (u8*)(P + 16777216);         // [4096][4096] fp8 (after wo_part)
    u16* w2_part = (u16*)(P + 33554432);    // 4x[4096][1024] bf16 (after att/flash done)

    mega_cvt<<<14848, 256, 0, stream>>>(wq, wk, wv, wo, w1, w3, w2,
                                        wqkv_bf, wo_bf, w13_8, w2_8);
    rmsnorm_kernel<<<4096, 256, 0, stream>>>(x, anw, xn_bf, 1e-5f);
    // QKV projection, split-K=2 -> bf16 partials
    gemm_bt<<<dim3(12, 32, 2), 256, 0, stream>>>(xn_bf, wqkv_bf, qkv_part,
                                                 4096, 1536, 1024, 512);
    qkv_post_kernel<<<4096, 256, 0, stream>>>(qkv_part, qnw, knw, Qb, Kb, Vb);
    flash_kernel<<<dim3(32, 16, 2), 256, 0, stream>>>(Qb, Kb, Vb, att_bf);
    // out-proj, split-K=2 -> bf16 partials
    gemm_bt<<<dim3(8, 32, 2), 256, 0, stream>>>(att_bf, wo_bf, wo_part,
                                                4096, 1024, 1024, 512);
    fuse_attn_kernel<<<4096, 256, 0, stream>>>(x, wo_part, ascale, fnw, h_f, xn8);
    // w1|w3 fp8-MX GEMM with fused SwiGLU -> gsw8
    gemm_fp8<1><<<dim3(64, 32, 1), 256, 0, stream>>>(xn8, w13_8, nullptr, gsw8,
                                                     4096, 8192, 1024, 1024);
    // w2 fp8-MX GEMM, split-K=4 -> bf16 partials
    gemm_fp8<0><<<dim3(8, 32, 4), 256, 0, stream>>>(gsw8, w2_8, w2_part, nullptr,
                                                    4096, 1024, 4096, 1024);
    fuse_ffn_kernel<<<4096, 256, 0, stream>>>(h_f, w2_part, fscale, out);
}

// Round 5
// 380.925 us; speedup vs baseline: 1.3124x; 1.0195x over previous
//
#include <hip/hip_runtime.h>

typedef unsigned short u16;
typedef unsigned int u32;
typedef unsigned char u8;
typedef short bf16x8 __attribute__((ext_vector_type(8)));
typedef float f32x4 __attribute__((ext_vector_type(4)));
typedef float f32x16 __attribute__((ext_vector_type(16)));
typedef int i32x4 __attribute__((ext_vector_type(4)));
typedef int i32x8 __attribute__((ext_vector_type(8)));

#define AS1 __attribute__((address_space(1)))
#define AS3 __attribute__((address_space(3)))

#define B_ 2
#define T_ 2048
#define DIM_ 1024
#define HID_ 4096
#define H_ 16
#define KVH_ 4
#define HD_ 64
#define WIN_ 512

// MX scale bytes: activations stored x8 (descale 2^-3 = 124), weights x64 (2^-6 = 121)
#define SCALE_A 0x7C7C7C7C
#define SCALE_B 0x79797979

__device__ __forceinline__ u16 f2bf(float f) {
    union { float f; u32 u; } v; v.f = f;
    u32 r = v.u + 0x7FFFu + ((v.u >> 16) & 1u);
    return (u16)(r >> 16);
}
__device__ __forceinline__ float bf2f(u32 u) {
    union { u32 u; float f; } v; v.u = u << 16;
    return v.f;
}
__device__ __forceinline__ float4 ld4bf(const u16* p) {
    uint2 u = *(const uint2*)p;
    float4 r;
    r.x = bf2f(u.x & 0xFFFFu); r.y = bf2f(u.x >> 16);
    r.z = bf2f(u.y & 0xFFFFu); r.w = bf2f(u.y >> 16);
    return r;
}
__device__ __forceinline__ void load_lds16(const void* g, void* l) {
    __builtin_amdgcn_global_load_lds((AS1 void*)(g), (AS3 void*)(l), 16, 0, 0);
}

// ---------------- mega convert: bf16 for wqkv/wo, fp8(x64) for w13 (interleaved-32) & w2 ----------------
__global__ __launch_bounds__(256) void mega_cvt(const float* __restrict__ wq,
                                                const float* __restrict__ wk,
                                                const float* __restrict__ wv,
                                                const float* __restrict__ wo,
                                                const float* __restrict__ w1,
                                                const float* __restrict__ w3,
                                                const float* __restrict__ w2,
                                                u16* __restrict__ wqkv,
                                                u16* __restrict__ wo_b,
                                                u8* __restrict__ w13_8,
                                                u8* __restrict__ w2_8) {
    int i = blockIdx.x * 256 + threadIdx.x;  // global float4 index, < 3801088 exactly
    if (i < 655360) {
        const float* s; uint2* dbase; size_t didx;
        if (i < 262144)      { s = wq + (size_t)i * 4; dbase = (uint2*)wqkv; didx = i; }
        else if (i < 327680) { int f = i - 262144; s = wk + (size_t)f * 4; dbase = (uint2*)wqkv; didx = 262144 + f; }
        else if (i < 393216) { int f = i - 327680; s = wv + (size_t)f * 4; dbase = (uint2*)wqkv; didx = 327680 + f; }
        else                 { int f = i - 393216; s = wo + (size_t)f * 4; dbase = (uint2*)wo_b; didx = f; }
        float4 v = *(const float4*)s;
        u32 lo = (u32)f2bf(v.x) | ((u32)f2bf(v.y) << 16);
        u32 hi = (u32)f2bf(v.z) | ((u32)f2bf(v.w) << 16);
        dbase[didx] = make_uint2(lo, hi);
    } else {
        // fp8 e4m3, values x64. w1/w3 interleaved in 32-col tiles:
        //   w1 row c -> packed (c>>5)*64 + (c&31);  w3 row c -> packed (c>>5)*64 + 32 + (c&31)
        const float* s; u32* dbase; size_t didx;
        if (i < 1703936)      { int f = i - 655360;  int c = f >> 8; int n = (c >> 5) * 64 + (c & 31);
                                s = w1 + (size_t)f * 4; dbase = (u32*)w13_8; didx = (size_t)n * 256 + (f & 255); }
        else if (i < 2752512) { int f = i - 1703936; int c = f >> 8; int n = (c >> 5) * 64 + 32 + (c & 31);
                                s = w3 + (size_t)f * 4; dbase = (u32*)w13_8; didx = (size_t)n * 256 + (f & 255); }
        else                  { int f = i - 2752512; s = w2 + (size_t)f * 4; dbase = (u32*)w2_8; didx = f; }
        float4 v = *(const float4*)s;
        int p = __builtin_amdgcn_cvt_pk_fp8_f32(v.x * 64.f, v.y * 64.f, 0, false);
        p = __builtin_amdgcn_cvt_pk_fp8_f32(v.z * 64.f, v.w * 64.f, p, true);
        dbase[didx] = (u32)p;
    }
}

// ---------------- RMSNorm (fp32 in, bf16 out), dim=1024 ----------------
__global__ __launch_bounds__(256) void rmsnorm_kernel(const float* __restrict__ x,
                                                      const float* __restrict__ w,
                                                      u16* __restrict__ out, float eps) {
    int row = blockIdx.x, tid = threadIdx.x;
    const float4 v = ((const float4*)(x + (size_t)row * DIM_))[tid];
    float ss = v.x * v.x + v.y * v.y + v.z * v.z + v.w * v.w;
#pragma unroll
    for (int m = 1; m < 64; m <<= 1) ss += __shfl_xor(ss, m);
    __shared__ float part[4];
    if ((tid & 63) == 0) part[tid >> 6] = ss;
    __syncthreads();
    float tot = part[0] + part[1] + part[2] + part[3];
    float r = rsqrtf(tot * (1.0f / DIM_) + eps);
    const float4 wv = ((const float4*)w)[tid];
    u32 lo = (u32)f2bf(v.x * r * wv.x) | ((u32)f2bf(v.y * r * wv.y) << 16);
    u32 hi = (u32)f2bf(v.z * r * wv.z) | ((u32)f2bf(v.w * r * wv.w) << 16);
    ((uint2*)(out + (size_t)row * DIM_))[tid] = make_uint2(lo, hi);
}

// ---------------- fuse_attn: h = x + (p0+p1)*ascale; xn8 = fp8(rmsnorm(h)*fnw * 8) ----------------
__global__ __launch_bounds__(256) void fuse_attn_kernel(const float* __restrict__ x,
                                                        const u16* __restrict__ p,
                                                        const float* __restrict__ ascale,
                                                        const float* __restrict__ fnw,
                                                        float* __restrict__ h,
                                                        u8* __restrict__ xn8) {
    int row = blockIdx.x, tid = threadIdx.x;
    const float4 xv = ((const float4*)(x + (size_t)row * DIM_))[tid];
    float4 a0 = ld4bf(p + (size_t)row * DIM_ + tid * 4);
    float4 a1 = ld4bf(p + 4194304 + (size_t)row * DIM_ + tid * 4);
    const float4 sc = ((const float4*)ascale)[tid];
    float4 hv;
    hv.x = xv.x + (a0.x + a1.x) * sc.x;
    hv.y = xv.y + (a0.y + a1.y) * sc.y;
    hv.z = xv.z + (a0.z + a1.z) * sc.z;
    hv.w = xv.w + (a0.w + a1.w) * sc.w;
    ((float4*)(h + (size_t)row * DIM_))[tid] = hv;
    float ss = hv.x * hv.x + hv.y * hv.y + hv.z * hv.z + hv.w * hv.w;
#pragma unroll
    for (int m = 1; m < 64; m <<= 1) ss += __shfl_xor(ss, m);
    __shared__ float part[4];
    if ((tid & 63) == 0) part[tid >> 6] = ss;
    __syncthreads();
    float tot = part[0] + part[1] + part[2] + part[3];
    float r = rsqrtf(tot * (1.0f / DIM_) + 1e-5f) * 8.0f;  // x8 for fp8 encoding
    const float4 wv = ((const float4*)fnw)[tid];
    int pk = __builtin_amdgcn_cvt_pk_fp8_f32(hv.x * r * wv.x, hv.y * r * wv.y, 0, false);
    pk = __builtin_amdgcn_cvt_pk_fp8_f32(hv.z * r * wv.z, hv.w * r * wv.w, pk, true);
    ((u32*)xn8)[(size_t)row * 256 + tid] = (u32)pk;
}

// ---------------- fuse_ffn: out = h + (p0+p1+p2+p3)*fscale (bf16 partials) ----------------
__global__ __launch_bounds__(256) void fuse_ffn_kernel(const float* __restrict__ h,
                                                       const u16* __restrict__ p,
                                                       const float* __restrict__ fscale,
                                                       float* __restrict__ out) {
    int row = blockIdx.x, tid = threadIdx.x;
    const float4 hv = ((const float4*)(h + (size_t)row * DIM_))[tid];
    size_t off = (size_t)row * DIM_ + tid * 4;
    float4 a0 = ld4bf(p + off);
    float4 a1 = ld4bf(p + 4194304 + off);
    float4 a2 = ld4bf(p + 8388608 + off);
    float4 a3 = ld4bf(p + 12582912 + off);
    const float4 sc = ((const float4*)fscale)[tid];
    float4 o;
    o.x = hv.x + (a0.x + a1.x + a2.x + a3.x) * sc.x;
    o.y = hv.y + (a0.y + a1.y + a2.y + a3.y) * sc.y;
    o.z = hv.z + (a0.z + a1.z + a2.z + a3.z) * sc.z;
    o.w = hv.w + (a0.w + a1.w + a2.w + a3.w) * sc.w;
    ((float4*)(out + (size_t)row * DIM_))[tid] = o;
}

// ---------------- QKV post: sum 2 bf16 partials + per-head RMSNorm(1e-6) + bf16 pack ----------------
__global__ __launch_bounds__(256) void qkv_post_kernel(const u16* __restrict__ qkv,
                                                       const float* __restrict__ qw,
                                                       const float* __restrict__ kw,
                                                       u16* __restrict__ Qb,
                                                       u16* __restrict__ Kb,
                                                       u16* __restrict__ Vb) {
    int bt = blockIdx.x;
    int b = bt >> 11, t = bt & (T_ - 1);
    int wave = threadIdx.x >> 6, lane = threadIdx.x & 63;
    const u16* row0 = qkv + (size_t)bt * 1536;
    const u16* row1 = row0 + 6291456;
    float qwl = qw[lane], kwl = kw[lane];
#pragma unroll
    for (int i = 0; i < 4; i++) {
        int h = wave * 4 + i;
        float v = bf2f(row0[h * 64 + lane]) + bf2f(row1[h * 64 + lane]);
        float ss = v * v;
#pragma unroll
        for (int m = 1; m < 64; m <<= 1) ss += __shfl_xor(ss, m);
        float r = rsqrtf(ss * (1.0f / 64.0f) + 1e-6f);
        Qb[(((size_t)(b * H_ + h)) * T_ + t) * HD_ + lane] = f2bf(v * r * qwl);
    }
    {
        float v = bf2f(row0[1024 + wave * 64 + lane]) + bf2f(row1[1024 + wave * 64 + lane]);
        float ss = v * v;
#pragma unroll
        for (int m = 1; m < 64; m <<= 1) ss += __shfl_xor(ss, m);
        float r = rsqrtf(ss * (1.0f / 64.0f) + 1e-6f);
        Kb[(((size_t)(b * KVH_ + wave)) * T_ + t) * HD_ + lane] = f2bf(v * r * kwl);
        float vv = bf2f(row0[1280 + wave * 64 + lane]) + bf2f(row1[1280 + wave * 64 + lane]);
        Vb[(((size_t)(b * KVH_ + wave)) * T_ + t) * HD_ + lane] = f2bf(vv);
    }
}

// ---------------- Flash attention, sliding window 512, GQA 16/4 ----------------
__global__ __launch_bounds__(256) void flash_kernel(const u16* __restrict__ Qb,
                                                    const u16* __restrict__ Kb,
                                                    const u16* __restrict__ Vb,
                                                    u16* __restrict__ Ob) {
    const int b = blockIdx.z, h = blockIdx.y, qt = blockIdx.x;
    const int q0 = qt * 64;
    const int tid = threadIdx.x, wave = tid >> 6, lane = tid & 63;
    const int m = lane & 15, quad = lane >> 4;
    const int kvh = h >> 2;

    __shared__ __align__(16) u16 Ks[32 * 64];
    __shared__ __align__(16) u16 Vts[64 * 32];
    __shared__ __align__(16) u16 Ps[4][16 * 32];

    const u16* Qp = Qb + ((size_t)(b * H_ + h) * T_) * HD_;
    const u16* Kp = Kb + ((size_t)(b * KVH_ + kvh) * T_) * HD_;
    const u16* Vp = Vb + ((size_t)(b * KVH_ + kvh) * T_) * HD_;

    const int qrow = q0 + wave * 16 + m;
    bf16x8 qa0 = *(const bf16x8*)(Qp + (size_t)qrow * 64 + quad * 8);
    bf16x8 qa1 = *(const bf16x8*)(Qp + (size_t)qrow * 64 + 32 + quad * 8);

    f32x4 o0 = {0.f, 0.f, 0.f, 0.f}, o1 = {0.f, 0.f, 0.f, 0.f};
    f32x4 o2 = {0.f, 0.f, 0.f, 0.f}, o3 = {0.f, 0.f, 0.f, 0.f};
    float mrun[4] = {-INFINITY, -INFINITY, -INFINITY, -INFINITY};
    float lrun[4] = {0.f, 0.f, 0.f, 0.f};

    const int klo = (q0 - (WIN_ - 1) > 0) ? (q0 - (WIN_ - 1)) : 0;
    const int kt0 = klo >> 5, kt1 = (q0 + 63) >> 5;
    const int qlo_w = q0 + wave * 16, qhi_w = qlo_w + 15;

    for (int kt = kt0; kt <= kt1; ++kt) {
        const int kbase = kt << 5;
        __syncthreads();
        {
            int flat = tid * 8;
            int kr = flat >> 6, d = flat & 63;
            *(bf16x8*)&Ks[flat] = *(const bf16x8*)(Kp + (size_t)(kbase + kr) * 64 + d);
            bf16x8 vv = *(const bf16x8*)(Vp + (size_t)(kbase + kr) * 64 + d);
#pragma unroll
            for (int jj = 0; jj < 8; jj++) Vts[(d + jj) * 32 + kr] = (u16)vv[jj];
        }
        __syncthreads();
        bool active = (kbase <= qhi_w) && (kbase + 31 >= qlo_w - (WIN_ - 1));
        if (active) {
            f32x4 s0 = {0.f, 0.f, 0.f, 0.f}, s1 = {0.f, 0.f, 0.f, 0.f};
            bf16x8 k00 = *(const bf16x8*)&Ks[m * 64 + quad * 8];
            bf16x8 k01 = *(const bf16x8*)&Ks[m * 64 + 32 + quad * 8];
            bf16x8 k10 = *(const bf16x8*)&Ks[(m + 16) * 64 + quad * 8];
            bf16x8 k11 = *(const bf16x8*)&Ks[(m + 16) * 64 + 32 + quad * 8];
            s0 = __builtin_amdgcn_mfma_f32_16x16x32_bf16(qa0, k00, s0, 0, 0, 0);
            s0 = __builtin_amdgcn_mfma_f32_16x16x32_bf16(qa1, k01, s0, 0, 0, 0);
            s1 = __builtin_amdgcn_mfma_f32_16x16x32_bf16(qa0, k10, s1, 0, 0, 0);
            s1 = __builtin_amdgcn_mfma_f32_16x16x32_bf16(qa1, k11, s1, 0, 0, 0);
#pragma unroll
            for (int r = 0; r < 4; r++) {
                int qg = q0 + wave * 16 + quad * 4 + r;
                int kg0 = kbase + m, kg1 = kbase + 16 + m;
                float v0 = (kg0 <= qg && qg - kg0 < WIN_) ? s0[r] * 0.125f : -INFINITY;
                float v1 = (kg1 <= qg && qg - kg1 < WIN_) ? s1[r] * 0.125f : -INFINITY;
                float rmax = fmaxf(v0, v1);
                rmax = fmaxf(rmax, __shfl_xor(rmax, 1));
                rmax = fmaxf(rmax, __shfl_xor(rmax, 2));
                rmax = fmaxf(rmax, __shfl_xor(rmax, 4));
                rmax = fmaxf(rmax, __shfl_xor(rmax, 8));
                float mnew = fmaxf(mrun[r], rmax);
                float alpha, p0, p1;
                if (mnew == -INFINITY) { alpha = 1.f; p0 = 0.f; p1 = 0.f; }
                else {
                    alpha = __expf(mrun[r] - mnew);
                    p0 = __expf(v0 - mnew);
                    p1 = __expf(v1 - mnew);
                }
                float psum = p0 + p1;
                psum += __shfl_xor(psum, 1);
                psum += __shfl_xor(psum, 2);
                psum += __shfl_xor(psum, 4);
                psum += __shfl_xor(psum, 8);
                lrun[r] = lrun[r] * alpha + psum;
                mrun[r] = mnew;
                o0[r] *= alpha; o1[r] *= alpha; o2[r] *= alpha; o3[r] *= alpha;
                Ps[wave][(quad * 4 + r) * 32 + m] = f2bf(p0);
                Ps[wave][(quad * 4 + r) * 32 + 16 + m] = f2bf(p1);
            }
            bf16x8 pa = *(const bf16x8*)&Ps[wave][m * 32 + quad * 8];
            bf16x8 vb0 = *(const bf16x8*)&Vts[(0 + m) * 32 + quad * 8];
            bf16x8 vb1 = *(const bf16x8*)&Vts[(16 + m) * 32 + quad * 8];
            bf16x8 vb2 = *(const bf16x8*)&Vts[(32 + m) * 32 + quad * 8];
            bf16x8 vb3 = *(const bf16x8*)&Vts[(48 + m) * 32 + quad * 8];
            o0 = __builtin_amdgcn_mfma_f32_16x16x32_bf16(pa, vb0, o0, 0, 0, 0);
            o1 = __builtin_amdgcn_mfma_f32_16x16x32_bf16(pa, vb1, o1, 0, 0, 0);
            o2 = __builtin_amdgcn_mfma_f32_16x16x32_bf16(pa, vb2, o2, 0, 0, 0);
            o3 = __builtin_amdgcn_mfma_f32_16x16x32_bf16(pa, vb3, o3, 0, 0, 0);
        }
    }
#pragma unroll
    for (int r = 0; r < 4; r++) {
        int qg = q0 + wave * 16 + quad * 4 + r;
        float inv = 1.0f / lrun[r];
        size_t base = ((size_t)(b * T_ + qg)) * (H_ * HD_) + h * HD_;
        Ob[base + 0 + m] = f2bf(o0[r] * inv);
        Ob[base + 16 + m] = f2bf(o1[r] * inv);
        Ob[base + 32 + m] = f2bf(o2[r] * inv);
        Ob[base + 48 + m] = f2bf(o3[r] * inv);
    }
}

// ---------------- bf16 GEMM, double-buffered single-barrier K-loop ----------------
// Prefetch tile k+1 is issued AFTER the barrier (which drains tile k's loads via its
// implicit vmcnt(0)) so it overlaps the ds_read+MFMA of tile k.
__global__ __launch_bounds__(256) void gemm_bt(const u16* __restrict__ A,
                                               const u16* __restrict__ Bt,
                                               u16* __restrict__ Cb,
                                               int M, int N, int K, int KS) {
    __shared__ __align__(16) u16 As[2][4096];
    __shared__ __align__(16) u16 Bs[2][4096];
    const int tid = threadIdx.x, wave = tid >> 6, lane = tid & 63;
    const int m = lane & 15, quad = lane >> 4;
    const int m0 = blockIdx.y * 128, n0 = blockIdx.x * 128;
    const int wm = (wave >> 1) * 64, wn = (wave & 1) * 64;
    const int kb = blockIdx.z * KS;
    const int nIter = KS >> 5;
    const int slot = wave * 2;
    const int flat0 = slot * 512 + lane * 8;
    const int row0_ = flat0 >> 5, col0 = flat0 & 31;
    const int flat1 = (slot + 1) * 512 + lane * 8;
    const int row1_ = flat1 >> 5, col1 = flat1 & 31;

    f32x4 acc[4][4] = {};

    // prologue: stage tile 0 into buffer 0
    load_lds16(A + (size_t)(m0 + row0_) * K + kb + col0, &As[0][slot * 512]);
    load_lds16(Bt + (size_t)(n0 + row0_) * K + kb + col0, &Bs[0][slot * 512]);
    load_lds16(A + (size_t)(m0 + row1_) * K + kb + col1, &As[0][(slot + 1) * 512]);
    load_lds16(Bt + (size_t)(n0 + row1_) * K + kb + col1, &Bs[0][(slot + 1) * 512]);

    for (int it = 0; it < nIter; ++it) {
        __syncthreads();  // drains vmcnt -> tile `it` staged; all waves done computing it-1
        const int cur = it & 1;
        if (it + 1 < nIter) {
            const int nb = 1 - cur;
            const int k0 = kb + (it + 1) * 32;
            load_lds16(A + (size_t)(m0 + row0_) * K + k0 + col0, &As[nb][slot * 512]);
            load_lds16(Bt + (size_t)(n0 + row0_) * K + k0 + col0, &Bs[nb][slot * 512]);
            load_lds16(A + (size_t)(m0 + row1_) * K + k0 + col1, &As[nb][(slot + 1) * 512]);
            load_lds16(Bt + (size_t)(n0 + row1_) * K + k0 + col1, &Bs[nb][(slot + 1) * 512]);
        }
        bf16x8 af[4], bfr[4];
#pragma unroll
        for (int i = 0; i < 4; i++) af[i] = *(const bf16x8*)&As[cur][(wm + i * 16 + m) * 32 + quad * 8];
#pragma unroll
        for (int j = 0; j < 4; j++) bfr[j] = *(const bf16x8*)&Bs[cur][(wn + j * 16 + m) * 32 + quad * 8];
#pragma unroll
        for (int i = 0; i < 4; i++)
#pragma unroll
            for (int j = 0; j < 4; j++)
                acc[i][j] = __builtin_amdgcn_mfma_f32_16x16x32_bf16(af[i], bfr[j], acc[i][j], 0, 0, 0);
    }

    u16* Cz = Cb + (size_t)blockIdx.z * M * N;
#pragma unroll
    for (int i = 0; i < 4; i++) {
        int rowb = m0 + wm + i * 16 + quad * 4;
#pragma unroll
        for (int j = 0; j < 4; j++) {
            int col = n0 + wn + j * 16 + m;
#pragma unroll
            for (int r = 0; r < 4; r++)
                Cz[(size_t)(rowb + r) * N + col] = f2bf(acc[i][j][r]);
        }
    }
}

// ---------------- fp8 MX GEMM (32x32x64 f8f6f4), double-buffered single-barrier ----------------
// A [M][K] fp8 (x8), Bt [N][K] fp8 (x64). Tile 128x128, BK=64, 4 waves of 64x64 (2x2 32x32).
// LDS granule (c,r) = 16B chunk c of row r -> offset (c*128+r)*16.
// MODE 0: bf16 partials at z*M*N. MODE 1: fused SwiGLU (32-col interleave) -> fp8(x8).
template <int MODE>
__global__ __launch_bounds__(256) void gemm_fp8(const u8* __restrict__ A,
                                                const u8* __restrict__ Bt,
                                                u16* __restrict__ Cb,
                                                u8* __restrict__ C8,
                                                int M, int N, int K, int KS) {
    __shared__ __align__(16) u8 As[2][8192];
    __shared__ __align__(16) u8 Bs[2][8192];
    const int tid = threadIdx.x, wave = tid >> 6, lane = tid & 63;
    const int l31 = lane & 31, lh = lane >> 5;
    const int m0 = blockIdx.y * 128, n0 = blockIdx.x * 128;
    const int wm = (wave >> 1) * 64, wn = (wave & 1) * 64;
    const int kb = blockIdx.z * KS;
    const int nIter = KS >> 6;
    const int chunk0 = wave * 2;
    const int g0 = chunk0 * 64 + lane, c0 = g0 >> 7, r0 = g0 & 127;
    const int g1 = (chunk0 + 1) * 64 + lane, c1 = g1 >> 7, r1 = g1 & 127;

    f32x16 acc[2][2] = {};

    // prologue: stage tile 0 into buffer 0
    load_lds16(A + (size_t)(m0 + r0) * K + kb + c0 * 16, &As[0][chunk0 * 1024]);
    load_lds16(Bt + (size_t)(n0 + r0) * K + kb + c0 * 16, &Bs[0][chunk0 * 1024]);
    load_lds16(A + (size_t)(m0 + r1) * K + kb + c1 * 16, &As[0][(chunk0 + 1) * 1024]);
    load_lds16(Bt + (size_t)(n0 + r1) * K + kb + c1 * 16, &Bs[0][(chunk0 + 1) * 1024]);

    for (int it = 0; it < nIter; ++it) {
        __syncthreads();  // drains vmcnt -> tile `it` staged
        const int cur = it & 1;
        if (it + 1 < nIter) {
            const int nb = 1 - cur;
            const int k0 = kb + (it + 1) * 64;
            load_lds16(A + (size_t)(m0 + r0) * K + k0 + c0 * 16, &As[nb][chunk0 * 1024]);
            load_lds16(Bt + (size_t)(n0 + r0) * K + k0 + c0 * 16, &Bs[nb][chunk0 * 1024]);
            load_lds16(A + (size_t)(m0 + r1) * K + k0 + c1 * 16, &As[nb][(chunk0 + 1) * 1024]);
            load_lds16(Bt + (size_t)(n0 + r1) * K + k0 + c1 * 16, &Bs[nb][(chunk0 + 1) * 1024]);
        }
        i32x8 af[2], bfr[2];
#pragma unroll
        for (int i = 0; i < 2; i++) {
            union { i32x4 h[2]; i32x8 v; } u;
            u.h[0] = *(const i32x4*)&As[cur][((lh * 2 + 0) * 128 + wm + i * 32 + l31) * 16];
            u.h[1] = *(const i32x4*)&As[cur][((lh * 2 + 1) * 128 + wm + i * 32 + l31) * 16];
            af[i] = u.v;
        }
#pragma unroll
        for (int j = 0; j < 2; j++) {
            union { i32x4 h[2]; i32x8 v; } u;
            u.h[0] = *(const i32x4*)&Bs[cur][((lh * 2 + 0) * 128 + wn + j * 32 + l31) * 16];
            u.h[1] = *(const i32x4*)&Bs[cur][((lh * 2 + 1) * 128 + wn + j * 32 + l31) * 16];
            bfr[j] = u.v;
        }
#pragma unroll
        for (int i = 0; i < 2; i++)
#pragma unroll
            for (int j = 0; j < 2; j++)
                acc[i][j] = __builtin_amdgcn_mfma_scale_f32_32x32x64_f8f6f4(
                    af[i], bfr[j], acc[i][j], 0, 0, 0, SCALE_A, 0, SCALE_B);
    }

    if (MODE == 0) {
        u16* Cz = Cb + (size_t)blockIdx.z * M * N;
#pragma unroll
        for (int i = 0; i < 2; i++)
#pragma unroll
            for (int j = 0; j < 2; j++) {
                int col = n0 + wn + j * 32 + l31;
#pragma unroll
                for (int reg = 0; reg < 16; reg++) {
                    int row = m0 + wm + i * 32 + (reg & 3) + 8 * (reg >> 2) + 4 * lh;
                    Cz[(size_t)row * N + col] = f2bf(acc[i][j][reg]);
                }
            }
    } else {
        // SwiGLU: acc[i][0] = g1-tile, acc[i][1] = g3-tile for same 32 real cols
        int c = (n0 >> 1) + (wn >> 1) + l31;
#pragma unroll
        for (int i = 0; i < 2; i++)
#pragma unroll
            for (int reg = 0; reg < 16; reg++) {
                int row = m0 + wm + i * 32 + (reg & 3) + 8 * (reg >> 2) + 4 * lh;
                float g1 = acc[i][0][reg], g3 = acc[i][1][reg];
                float res = (g1 / (1.f + __expf(-g1))) * g3 * 8.0f;  // x8 for fp8 encoding
                int p = __builtin_amdgcn_cvt_pk_fp8_f32(res, res, 0, false);
                C8[(size_t)row * (N >> 1) + c] = (u8)(p & 0xFF);
            }
    }
}

extern "C" void kernel_launch(void* const* d_in, const int* in_sizes, int n_in,
                              void* d_out, int out_size, void* d_ws, size_t ws_size,
                              hipStream_t stream) {
    const float* x = (const float*)d_in[0];
    const float* wq = (const float*)d_in[1];
    const float* wk = (const float*)d_in[2];
    const float* wv = (const float*)d_in[3];
    const float* wo = (const float*)d_in[4];
    const float* w1 = (const float*)d_in[5];
    const float* w2 = (const float*)d_in[6];
    const float* w3 = (const float*)d_in[7];
    const float* qnw = (const float*)d_in[8];
    const float* knw = (const float*)d_in[9];
    const float* anw = (const float*)d_in[10];
    const float* fnw = (const float*)d_in[11];
    const float* ascale = (const float*)d_in[12];
    const float* fscale = (const float*)d_in[13];
    float* out = (float*)d_out;

    // ---- workspace layout (~109 MiB) ----
    char* ws = (char*)d_ws;
    u16* wqkv_bf = (u16*)(ws + 0);          // [1536][1024] bf16
    u16* wo_bf = (u16*)(ws + 3145728);      // [1024][1024] bf16
    u8* w13_8 = (u8*)(ws + 5242880);        // [8192][1024] fp8 (x64, 32-col interleave)
    u8* w2_8 = (u8*)(ws + 13631488);        // [1024][4096] fp8 (x64)
    u16* xn_bf = (u16*)(ws + 17825792);     // [4096][1024] bf16 (attn-norm out)
    u8* xn8 = (u8*)(ws + 26214400);         // [4096][1024] fp8 (x8, ffn-norm out)
    float* h_f = (float*)(ws + 30408704);   // [4096][1024] fp32
    char* P = ws + 47185920;                // overlay pool (67.1 MB)
    u16* qkv_part = (u16*)(P + 0);          // 2x[4096][1536] bf16 partials
    u16* Qb = (u16*)(P + 25165824);
    u16* Kb = (u16*)(P + 33554432);
    u16* Vb = (u16*)(P + 35651584);
    u16* att_bf = (u16*)(P + 37748736);     // [4096][1024] bf16
    u16* wo_part = (u16*)(P + 0);           // 2x[4096][1024] bf16 (reuses qkv_part)
    u8* gsw8 = (u8*)(P + 16777216);         // [4096][4096] fp8 (after wo_part)
    u16* w2_part = (u16*)(P + 33554432);    // 4x[4096][1024] bf16 (after att/flash done)

    mega_cvt<<<14848, 256, 0, stream>>>(wq, wk, wv, wo, w1, w3, w2,
                                        wqkv_bf, wo_bf, w13_8, w2_8);
    rmsnorm_kernel<<<4096, 256, 0, stream>>>(x, anw, xn_bf, 1e-5f);
    // QKV projection, split-K=2 -> bf16 partials
    gemm_bt<<<dim3(12, 32, 2), 256, 0, stream>>>(xn_bf, wqkv_bf, qkv_part,
                                                 4096, 1536, 1024, 512);
    qkv_post_kernel<<<4096, 256, 0, stream>>>(qkv_part, qnw, knw, Qb, Kb, Vb);
    flash_kernel<<<dim3(32, 16, 2), 256, 0, stream>>>(Qb, Kb, Vb, att_bf);
    // out-proj, split-K=2 -> bf16 partials
    gemm_bt<<<dim3(8, 32, 2), 256, 0, stream>>>(att_bf, wo_bf, wo_part,
                                                4096, 1024, 1024, 512);
    fuse_attn_kernel<<<4096, 256, 0, stream>>>(x, wo_part, ascale, fnw, h_f, xn8);
    // w1|w3 fp8-MX GEMM with fused SwiGLU -> gsw8
    gemm_fp8<1><<<dim3(64, 32, 1), 256, 0, stream>>>(xn8, w13_8, nullptr, gsw8,
                                                     4096, 8192, 1024, 1024);
    // w2 fp8-MX GEMM, split-K=4 -> bf16 partials
    gemm_fp8<0><<<dim3(8, 32, 4), 256, 0, stream>>>(gsw8, w2_8, w2_part, nullptr,
                                                    4096, 1024, 4096, 1024);
    fuse_ffn_kernel<<<4096, 256, 0, stream>>>(h_f, w2_part, fscale, out);
}